// Round 2
// baseline (3648.877 us; speedup 1.0000x reference)
//
#include <hip/hip_runtime.h>

#define BB 8192
#define DD 1024
#define HH 512
#define LL 64
#define KNN 15
#define CSPLIT 8
#define NEDGE (BB * KNN)

typedef __attribute__((ext_vector_type(4))) float f32x4;
typedef __attribute__((ext_vector_type(8))) short s16x8;
typedef __attribute__((ext_vector_type(8))) unsigned short u16x8;
typedef __attribute__((ext_vector_type(4))) unsigned short u16x4;
typedef __attribute__((ext_vector_type(4))) _Float16 f16x4;

typedef s16x8 fragT;

// ---------------- convert x -> bf16 + row norms ----------------
__global__ void k_convert(const float* __restrict__ x, unsigned short* __restrict__ xb,
                          float* __restrict__ sqx) {
  int row = blockIdx.x;
  int t = threadIdx.x;
  f32x4 v = *(const f32x4*)(x + (size_t)row * DD + t * 4);
  u16x4 o;
  float s = 0.f;
#pragma unroll
  for (int j = 0; j < 4; ++j) {
    float f = v[j];
    s += f * f;
    unsigned u = __float_as_uint(f);
    o[j] = (unsigned short)((u + 0x7fffu + ((u >> 16) & 1u)) >> 16);  // RNE
  }
  *(u16x4*)(xb + (size_t)row * DD + t * 4) = o;
#pragma unroll
  for (int off = 32; off >= 1; off >>= 1) s += __shfl_down(s, off);
  __shared__ float ps[4];
  if ((t & 63) == 0) ps[t >> 6] = s;
  __syncthreads();
  if (t == 0) sqx[row] = ps[0] + ps[1] + ps[2] + ps[3];
}

// ---------------- simple fp32 GEMM: C = act(A@W + bias) ----------------
template <int RELU, int FUSE>
__global__ void k_gemm(const float* __restrict__ A, const float* __restrict__ W,
                       const float* __restrict__ bias, float* __restrict__ C,
                       const float* __restrict__ Xref, float* __restrict__ rec_sum,
                       int M, int N, int Kd) {
  __shared__ float As[16][68];
  __shared__ float Ws[16][64];
  int t = threadIdx.x;
  int tx = t & 15, ty = t >> 4;
  int m0 = blockIdx.y * 64, n0 = blockIdx.x * 64;
  int ar = t >> 2, aq = t & 3;
  int wk = t >> 4, wq = t & 15;
  float acc[4][4] = {};
  for (int k0 = 0; k0 < Kd; k0 += 16) {
    f32x4 av = *(const f32x4*)(A + (size_t)(m0 + ar) * Kd + k0 + aq * 4);
    f32x4 wv = *(const f32x4*)(W + (size_t)(k0 + wk) * N + n0 + wq * 4);
    __syncthreads();
#pragma unroll
    for (int j = 0; j < 4; ++j) As[aq * 4 + j][ar] = av[j];
    *(f32x4*)&Ws[wk][wq * 4] = wv;
    __syncthreads();
#pragma unroll
    for (int kk = 0; kk < 16; ++kk) {
      f32x4 a4 = *(const f32x4*)&As[kk][ty * 4];
      f32x4 b4 = *(const f32x4*)&Ws[kk][tx * 4];
#pragma unroll
      for (int i = 0; i < 4; ++i)
#pragma unroll
        for (int j = 0; j < 4; ++j) acc[i][j] = fmaf(a4[i], b4[j], acc[i][j]);
    }
  }
  f32x4 bv = *(const f32x4*)(bias + n0 + tx * 4);
  if (FUSE) {
    float local = 0.f;
#pragma unroll
    for (int i = 0; i < 4; ++i) {
      int row = m0 + ty * 4 + i;
      f32x4 xv = *(const f32x4*)(Xref + (size_t)row * N + n0 + tx * 4);
#pragma unroll
      for (int j = 0; j < 4; ++j) {
        float c = acc[i][j] + bv[j];
        float d = c - xv[j];
        local = fmaf(d, d, local);
      }
    }
#pragma unroll
    for (int off = 32; off >= 1; off >>= 1) local += __shfl_down(local, off);
    __shared__ float rs[4];
    if ((t & 63) == 0) rs[t >> 6] = local;
    __syncthreads();
    if (t == 0) atomicAdd(rec_sum, rs[0] + rs[1] + rs[2] + rs[3]);
  } else {
#pragma unroll
    for (int i = 0; i < 4; ++i) {
      int row = m0 + ty * 4 + i;
      f32x4 o;
#pragma unroll
      for (int j = 0; j < 4; ++j) {
        float c = acc[i][j] + bv[j];
        if (RELU) c = fmaxf(c, 0.f);
        o[j] = c;
      }
      *(f32x4*)(C + (size_t)row * N + n0 + tx * 4) = o;
    }
  }
}

// ---------------- Gram (bf16 MFMA) + fused per-row top-15 ----------------
// block: 128 rows x (1024-col strip = 8 tiles of 128); 256 thr = 4 waves (2x2)
// LDS rows are 128B (BK=64), T2 swizzle byte ^= (row&7)<<4 stays in-row.
__global__ __launch_bounds__(256) void k_gram_topk(
    const unsigned short* __restrict__ xb, const float* __restrict__ sqx,
    float* __restrict__ part_d2, int* __restrict__ part_idx) {
  __shared__ unsigned short At[128 * 64];  // 16KB
  __shared__ unsigned short Bt[128 * 64];  // 16KB
  __shared__ _Float16 S[16384];            // 32KB [col][row] swizzled
  __shared__ float sqr[128], sqc[128];

  int bid = blockIdx.x;
  int rt = bid / CSPLIT, cs = bid - rt * CSPLIT;
  int r0 = rt * 128, cbase = cs * 1024;
  int t = threadIdx.x;
  int lane = t & 63, w = t >> 6;
  int wr = w >> 1, wc = w & 1;

  if (t < 128) sqr[t] = sqx[r0 + t];

  float ld[KNN];
  int li[KNN];
#pragma unroll
  for (int p = 0; p < KNN; ++p) { ld[p] = 3.0e38f; li[p] = -1; }

  // staging geometry: 1024 slots x 16B per buffer; slot s -> row s>>3, chunk s&7
  int srow[4], koff[4];
#pragma unroll
  for (int q = 0; q < 4; ++q) {
    int s = t + q * 256;
    int r = s >> 3, g = s & 7;
    srow[q] = r;
    koff[q] = (((g << 4) ^ ((r & 7) << 4)) >> 1);  // shorts within 64-short window
  }

  int lrow = lane & 15;
  int klo = (lane >> 4) << 4;            // byte group within k-half
  int sw = (lane & 7) << 4;              // T2 swizzle (row&7 == lane&7 for our rows)

  const char* Atc = (const char*)At;
  const char* Btc = (const char*)Bt;

  for (int tt = 0; tt < 8; ++tt) {
    int c0 = cbase + tt * 128;
    if (t < 128) sqc[t] = sqx[c0 + t];

    f32x4 acc[16] = {};

    const unsigned short* pA[4];
    const unsigned short* pB[4];
#pragma unroll
    for (int q = 0; q < 4; ++q) {
      pA[q] = xb + (size_t)(r0 + srow[q]) * DD + koff[q];
      pB[q] = xb + (size_t)(c0 + srow[q]) * DD + koff[q];
    }

    for (int kt = 0; kt < 16; ++kt) {
      u16x8 vA[4], vB[4];
#pragma unroll
      for (int q = 0; q < 4; ++q) {
        vA[q] = *(const u16x8*)pA[q];
        vB[q] = *(const u16x8*)pB[q];
        pA[q] += 64;
        pB[q] += 64;
      }
      __syncthreads();
#pragma unroll
      for (int q = 0; q < 4; ++q) {
        *(u16x8*)(At + (t + q * 256) * 8) = vA[q];
        *(u16x8*)(Bt + (t + q * 256) * 8) = vB[q];
      }
      __syncthreads();
#pragma unroll
      for (int kh = 0; kh < 2; ++kh) {
        fragT af[4], bf[4];
        int kbyte = ((kh << 6) | klo) ^ sw;
#pragma unroll
        for (int m = 0; m < 4; ++m)
          af[m] = *(const fragT*)(Atc + (wr * 64 + m * 16 + lrow) * 128 + kbyte);
#pragma unroll
        for (int n = 0; n < 4; ++n)
          bf[n] = *(const fragT*)(Btc + (wc * 64 + n * 16 + lrow) * 128 + kbyte);
#pragma unroll
        for (int m = 0; m < 4; ++m)
#pragma unroll
          for (int n = 0; n < 4; ++n)
            acc[m * 4 + n] =
                __builtin_amdgcn_mfma_f32_16x16x32_bf16(af[m], bf[n], acc[m * 4 + n], 0, 0, 0);
      }
    }

    __syncthreads();
    // write d2 into S (f16), self -> big sentinel
#pragma unroll
    for (int m = 0; m < 4; ++m) {
      int row0 = wr * 64 + m * 16 + ((lane >> 4) << 2);
      f32x4 sq4 = *(const f32x4*)&sqr[row0];
#pragma unroll
      for (int n = 0; n < 4; ++n) {
        int col = wc * 64 + n * 16 + (lane & 15);
        float sc = sqc[col];
        f32x4 a = acc[m * 4 + n];
        f16x4 hv;
#pragma unroll
        for (int r = 0; r < 4; ++r) {
          float d2 = sq4[r] + sc - 2.f * a[r];
          if (r0 + row0 + r == c0 + col) d2 = 65000.f;
          hv[r] = (_Float16)d2;
        }
        *(f16x4*)((char*)S + col * 256 + ((row0 * 2) ^ ((col & 7) << 3))) = hv;
      }
    }
    __syncthreads();
    if (t < 128) {
      int t2 = t * 2;
      for (int c = 0; c < 128; ++c) {
        float d = (float)*(const _Float16*)((const char*)S + c * 256 + (t2 ^ ((c & 7) << 3)));
        if (d < ld[KNN - 1]) {
          float v = d;
          int vi = c0 + c;
#pragma unroll
          for (int p = 0; p < KNN; ++p) {
            if (v < ld[p]) {
              float tv = ld[p]; int ti = li[p];
              ld[p] = v; li[p] = vi;
              v = tv; vi = ti;
            }
          }
        }
      }
    }
    __syncthreads();
  }

  if (t < 128) {
    size_t base = ((size_t)(r0 + t) * CSPLIT + cs) * KNN;
#pragma unroll
    for (int p = 0; p < KNN; ++p) {
      part_d2[base + p] = ld[p];
      part_idx[base + p] = li[p];
    }
  }
}

// ---------------- merge partial top-k, build directed bitmask, xmax ----------------
__global__ void k_merge(const float* __restrict__ part_d2, const int* __restrict__ part_idx,
                        float* __restrict__ knn_d2, int* __restrict__ knn_idx,
                        unsigned* __restrict__ Mdir, int* __restrict__ xmax_bits) {
  int i = blockIdx.x * 256 + threadIdx.x;
  float ld[KNN];
  int li[KNN];
#pragma unroll
  for (int p = 0; p < KNN; ++p) { ld[p] = 3.0e38f; li[p] = -1; }
  size_t base = (size_t)i * CSPLIT * KNN;
  for (int q = 0; q < CSPLIT * KNN; ++q) {
    float d = part_d2[base + q];
    int idx = part_idx[base + q];
    if (d < ld[KNN - 1]) {
      float v = d; int vi = idx;
#pragma unroll
      for (int p = 0; p < KNN; ++p) {
        if (v < ld[p]) {
          float tv = ld[p]; int ti = li[p];
          ld[p] = v; li[p] = vi;
          v = tv; vi = ti;
        }
      }
    }
  }
  float mx = 0.f;
#pragma unroll
  for (int p = 0; p < KNN; ++p) {
    float d = fmaxf(ld[p], 0.f);
    mx = fmaxf(mx, d);
    knn_d2[(size_t)i * KNN + p] = d;
    int j = li[p];
    knn_idx[(size_t)i * KNN + p] = j;
    atomicOr(&Mdir[(size_t)i * (BB / 32) + (j >> 5)], 1u << (j & 31));
  }
  atomicMax(xmax_bits, __float_as_int(mx));
}

// ---------------- per-edge z distances (exact fp32) + zmax ----------------
__global__ void k_edge_z(const float* __restrict__ z, const int* __restrict__ knn_idx,
                         float* __restrict__ zd2, int* __restrict__ zmax_bits) {
  int e = blockIdx.x * 4 + (threadIdx.x >> 6);
  int lane = threadIdx.x & 63;
  int i = e / KNN;
  int j = knn_idx[e];
  float zi = z[(size_t)i * LL + lane];
  float zj = z[(size_t)j * LL + lane];
  float d = zi - zj;
  float v = d * d;
#pragma unroll
  for (int off = 32; off >= 1; off >>= 1) v += __shfl_down(v, off);
  if (lane == 0) {
    zd2[e] = v;
    atomicMax(zmax_bits, __float_as_int(v));
  }
}

// ---------------- edge loss accumulation ----------------
__global__ void k_loss(const float* __restrict__ knn_d2, const int* __restrict__ knn_idx,
                       const float* __restrict__ zd2, const unsigned* __restrict__ Mdir,
                       const int* __restrict__ xmax_bits, const int* __restrict__ zmax_bits,
                       float* __restrict__ loss_sum, float* __restrict__ cnt_sum) {
  int e = blockIdx.x * 256 + threadIdx.x;
  float inv_x = 1.f / (sqrtf(__int_as_float(*xmax_bits)) + 1e-8f);
  float inv_z = 1.f / (sqrtf(__int_as_float(*zmax_bits)) + 1e-8f);
  int i = e / KNN;
  int j = knn_idx[e];
  unsigned bit = (Mdir[(size_t)j * (BB / 32) + (i >> 5)] >> (i & 31)) & 1u;
  float wgt = bit ? 1.f : 2.f;  // reciprocal edge counted once each direction
  float xd = sqrtf(knn_d2[e]);
  float zd = sqrtf(fmaxf(zd2[e], 0.f));
  float diff = zd * inv_z - xd * inv_x;
  float c1 = wgt * diff * diff;
  float c2 = wgt;
#pragma unroll
  for (int off = 32; off >= 1; off >>= 1) {
    c1 += __shfl_down(c1, off);
    c2 += __shfl_down(c2, off);
  }
  __shared__ float r1[4], r2[4];
  int t = threadIdx.x;
  if ((t & 63) == 0) { r1[t >> 6] = c1; r2[t >> 6] = c2; }
  __syncthreads();
  if (t == 0) {
    atomicAdd(loss_sum, r1[0] + r1[1] + r1[2] + r1[3]);
    atomicAdd(cnt_sum, r2[0] + r2[1] + r2[2] + r2[3]);
  }
}

__global__ void k_final(const float* __restrict__ rec_sum, const float* __restrict__ loss_sum,
                        const float* __restrict__ cnt_sum, float* __restrict__ out) {
  if (threadIdx.x == 0)
    out[0] = rec_sum[0] * (1.f / 8388608.f) + loss_sum[0] / cnt_sum[0];
}

extern "C" void kernel_launch(void* const* d_in, const int* in_sizes, int n_in,
                              void* d_out, int out_size, void* d_ws, size_t ws_size,
                              hipStream_t stream) {
  const float* x = (const float*)d_in[0];
  const float* We1 = (const float*)d_in[1];
  const float* be1 = (const float*)d_in[2];
  const float* We2 = (const float*)d_in[3];
  const float* be2 = (const float*)d_in[4];
  const float* Wd1 = (const float*)d_in[5];
  const float* bd1 = (const float*)d_in[6];
  const float* Wd2 = (const float*)d_in[7];
  const float* bd2 = (const float*)d_in[8];

  char* ws = (char*)d_ws;
  size_t off = 0;
  auto alloc = [&](size_t bytes) {
    void* p = ws + off;
    off += (bytes + 255) & ~(size_t)255;
    return p;
  };
  unsigned short* xb = (unsigned short*)alloc((size_t)BB * DD * 2);
  float* h = (float*)alloc((size_t)BB * HH * 4);
  float* z = (float*)alloc((size_t)BB * LL * 4);
  float* h2 = (float*)alloc((size_t)BB * HH * 4);
  float* sqx = (float*)alloc((size_t)BB * 4);
  float* part_d2 = (float*)alloc((size_t)BB * CSPLIT * KNN * 4);
  int* part_idx = (int*)alloc((size_t)BB * CSPLIT * KNN * 4);
  float* knn_d2 = (float*)alloc((size_t)BB * KNN * 4);
  int* knn_idx = (int*)alloc((size_t)BB * KNN * 4);
  float* zd2 = (float*)alloc((size_t)BB * KNN * 4);
  unsigned* Mdir = (unsigned*)alloc((size_t)BB * (BB / 32) * 4);
  float* scal = (float*)alloc(64);
  float* rec_sum = scal + 0;
  float* loss_sum = scal + 1;
  float* cnt_sum = scal + 2;
  int* xmax_bits = (int*)(scal + 3);
  int* zmax_bits = (int*)(scal + 4);

  hipMemsetAsync(Mdir, 0, (size_t)BB * (BB / 32) * 4, stream);
  hipMemsetAsync(scal, 0, 64, stream);

  k_convert<<<BB, 256, 0, stream>>>(x, xb, sqx);
  k_gemm<1, 0><<<dim3(HH / 64, BB / 64), 256, 0, stream>>>(x, We1, be1, h, nullptr, nullptr, BB, HH, DD);
  k_gemm<0, 0><<<dim3(LL / 64, BB / 64), 256, 0, stream>>>(h, We2, be2, z, nullptr, nullptr, BB, LL, HH);
  k_gemm<1, 0><<<dim3(HH / 64, BB / 64), 256, 0, stream>>>(z, Wd1, bd1, h2, nullptr, nullptr, BB, HH, LL);
  k_gemm<0, 1><<<dim3(DD / 64, BB / 64), 256, 0, stream>>>(h2, Wd2, bd2, nullptr, x, rec_sum, BB, DD, HH);
  k_gram_topk<<<(BB / 128) * CSPLIT, 256, 0, stream>>>(xb, sqx, part_d2, part_idx);
  k_merge<<<BB / 256, 256, 0, stream>>>(part_d2, part_idx, knn_d2, knn_idx, Mdir, xmax_bits);
  k_edge_z<<<NEDGE / 4, 256, 0, stream>>>(z, knn_idx, zd2, zmax_bits);
  k_loss<<<NEDGE / 256, 256, 0, stream>>>(knn_d2, knn_idx, zd2, Mdir, xmax_bits, zmax_bits,
                                          loss_sum, cnt_sum);
  k_final<<<1, 64, 0, stream>>>(rec_sum, loss_sum, cnt_sum, (float*)d_out);
}

// Round 3
// 2889.272 us; speedup vs baseline: 1.2629x; 1.2629x over previous
//
#include <hip/hip_runtime.h>

#define BB 8192
#define DD 1024
#define HH 512
#define LL 64
#define KNN 15
#define CSPLIT 8
#define NEDGE (BB * KNN)

typedef __attribute__((ext_vector_type(4))) float f32x4;
typedef __attribute__((ext_vector_type(8))) short s16x8;
typedef __attribute__((ext_vector_type(8))) unsigned short u16x8;
typedef __attribute__((ext_vector_type(4))) unsigned short u16x4;
typedef __attribute__((ext_vector_type(4))) _Float16 f16x4;

typedef s16x8 fragT;

__device__ __forceinline__ unsigned short f2bf(float f) {
  unsigned u = __float_as_uint(f);
  return (unsigned short)((u + 0x7fffu + ((u >> 16) & 1u)) >> 16);  // RNE
}

__device__ __forceinline__ void gload16(const void* g, void* l) {
  __builtin_amdgcn_global_load_lds((const __attribute__((address_space(1))) unsigned int*)g,
                                   (__attribute__((address_space(3))) unsigned int*)l, 16, 0, 0);
}

// ---------------- convert x -> bf16 + row norms ----------------
__global__ void k_convert(const float* __restrict__ x, unsigned short* __restrict__ xb,
                          float* __restrict__ sqx) {
  int row = blockIdx.x;
  int t = threadIdx.x;
  f32x4 v = *(const f32x4*)(x + (size_t)row * DD + t * 4);
  u16x4 o;
  float s = 0.f;
#pragma unroll
  for (int j = 0; j < 4; ++j) {
    float f = v[j];
    s += f * f;
    o[j] = f2bf(f);
  }
  *(u16x4*)(xb + (size_t)row * DD + t * 4) = o;
#pragma unroll
  for (int off = 32; off >= 1; off >>= 1) s += __shfl_down(s, off);
  __shared__ float ps[4];
  if ((t & 63) == 0) ps[t >> 6] = s;
  __syncthreads();
  if (t == 0) sqx[row] = ps[0] + ps[1] + ps[2] + ps[3];
}

// ---------------- weight transpose+convert: W (K x N) f32 -> Wt (N x K) bf16 ----------------
__global__ void k_wt(const float* __restrict__ W, unsigned short* __restrict__ Wt, int Kd, int N) {
  __shared__ unsigned short T[64][65];
  int k0 = blockIdx.x * 64, n0 = blockIdx.y * 64;
  int t = threadIdx.x;
  int kr = t >> 4, nc = (t & 15) * 4;
#pragma unroll
  for (int q = 0; q < 4; ++q) {
    int k = kr + q * 16;
    f32x4 v = *(const f32x4*)(W + (size_t)(k0 + k) * N + n0 + nc);
#pragma unroll
    for (int j = 0; j < 4; ++j) T[nc + j][k] = f2bf(v[j]);
  }
  __syncthreads();
#pragma unroll
  for (int q = 0; q < 2; ++q) {
    int s = t + q * 256;
    int n = s >> 3, c = (s & 7) * 8;
    u16x8 o;
#pragma unroll
    for (int j = 0; j < 8; ++j) o[j] = T[n][c + j];
    *(u16x8*)(Wt + (size_t)(n0 + n) * Kd + k0 + c) = o;
  }
}

// ---------------- bf16 MFMA GEMM: C = act(A @ Wt^T + bias) ----------------
// A: M x Kd bf16 row-major; Wt: N x Kd bf16 row-major. 256 thr, 2x2 waves,
// tile 128 x (NF*32). T2-swizzled LDS staged via global_load_lds.
template <int NF, int RELU, int FUSE, int STF32, int STBF>
__global__ __launch_bounds__(256) void k_mgemm(
    const unsigned short* __restrict__ A, const unsigned short* __restrict__ Wt,
    const float* __restrict__ bias, unsigned short* __restrict__ Cb, float* __restrict__ Cf,
    const float* __restrict__ Xref, float* __restrict__ rec_sum, int N, int Kd) {
  __shared__ __attribute__((aligned(16))) unsigned short At[128 * 64];
  __shared__ __attribute__((aligned(16))) unsigned short Bt[NF * 32 * 64];
  int t = threadIdx.x;
  int lane = t & 63, w = t >> 6;
  int wr = w >> 1, wc = w & 1;
  int wbase = w * 64;
  int m0 = blockIdx.y * 128, n0 = blockIdx.x * (NF * 32);

  int srow[4], ksh[4];
#pragma unroll
  for (int q = 0; q < 4; ++q) {
    int s = q * 256 + t;
    int r = s >> 3, g = s & 7;
    srow[q] = r;
    ksh[q] = (g ^ (r & 7)) * 8;  // shorts
  }

  int lrow = lane & 15;
  int klo = (lane >> 4) << 4;
  int sw = (lane & 7) << 4;

  f32x4 acc[4][NF] = {};

  int ksteps = Kd >> 6;
  for (int kt = 0; kt < ksteps; ++kt) {
    int kb = kt << 6;
#pragma unroll
    for (int q = 0; q < 4; ++q)
      gload16(A + (size_t)(m0 + srow[q]) * Kd + kb + ksh[q], At + (q * 256 + wbase) * 8);
#pragma unroll
    for (int q = 0; q < NF; ++q)
      gload16(Wt + (size_t)(n0 + srow[q]) * Kd + kb + ksh[q], Bt + (q * 256 + wbase) * 8);
    __syncthreads();
#pragma unroll
    for (int kh = 0; kh < 2; ++kh) {
      int kbyte = ((kh << 6) | klo) ^ sw;
      fragT af[4], bf[NF];
#pragma unroll
      for (int m = 0; m < 4; ++m)
        af[m] = *(const fragT*)((const char*)At + (wr * 64 + m * 16 + lrow) * 128 + kbyte);
#pragma unroll
      for (int n = 0; n < NF; ++n)
        bf[n] = *(const fragT*)((const char*)Bt + (wc * NF * 16 + n * 16 + lrow) * 128 + kbyte);
#pragma unroll
      for (int m = 0; m < 4; ++m)
#pragma unroll
        for (int n = 0; n < NF; ++n)
          acc[m][n] = __builtin_amdgcn_mfma_f32_16x16x32_bf16(af[m], bf[n], acc[m][n], 0, 0, 0);
    }
    __syncthreads();
  }

  float local = 0.f;
#pragma unroll
  for (int m = 0; m < 4; ++m) {
    int row0 = m0 + wr * 64 + m * 16 + ((lane >> 4) << 2);
#pragma unroll
    for (int n = 0; n < NF; ++n) {
      int col = n0 + wc * NF * 16 + n * 16 + lrow;
      float bv = bias[col];
      f32x4 a = acc[m][n];
#pragma unroll
      for (int j = 0; j < 4; ++j) {
        float c = a[j] + bv;
        if (RELU) c = fmaxf(c, 0.f);
        if (FUSE) {
          float xv = Xref[(size_t)(row0 + j) * N + col];
          float d = c - xv;
          local = fmaf(d, d, local);
        }
        if (STBF) Cb[(size_t)(row0 + j) * N + col] = f2bf(c);
        if (STF32) Cf[(size_t)(row0 + j) * N + col] = c;
      }
    }
  }
  if (FUSE) {
#pragma unroll
    for (int off = 32; off >= 1; off >>= 1) local += __shfl_down(local, off);
    __shared__ float rs[4];
    if ((t & 63) == 0) rs[t >> 6] = local;
    __syncthreads();
    if (t == 0) atomicAdd(rec_sum, rs[0] + rs[1] + rs[2] + rs[3]);
  }
}

// ---------------- Gram (bf16 MFMA) + fused per-row top-15 ----------------
// block: 128 rows x 1024-col strip (8 tiles of 128); 256 thr = 4 waves (2x2)
// LDS 49KB -> 3 blocks/CU. global_load_lds staging, T2 swizzle.
__global__ __launch_bounds__(256) void k_gram_topk(
    const unsigned short* __restrict__ xb, const float* __restrict__ sqx,
    float* __restrict__ part_d2, int* __restrict__ part_idx) {
  __shared__ __attribute__((aligned(16))) unsigned short At[128 * 64];  // 16KB
  __shared__ __attribute__((aligned(16))) unsigned short Bt[128 * 64];  // 16KB
  __shared__ __attribute__((aligned(16))) _Float16 S[64 * 128];         // 16KB [col 64][row 128]
  __shared__ float sqr[128], sqc[128];

  int bid = blockIdx.x;
  int rt = bid >> 3, cs = bid & 7;  // cs == bid%8 == XCD -> one col-strip per XCD
  int r0 = rt * 128, cbase = cs * 1024;
  int t = threadIdx.x;
  int lane = t & 63, w = t >> 6;
  int wr = w >> 1, wc = w & 1;
  int wbase = w * 64;

  if (t < 128) sqr[t] = sqx[r0 + t];

  float ld[KNN];
  int li[KNN];
#pragma unroll
  for (int p = 0; p < KNN; ++p) { ld[p] = 3.0e38f; li[p] = -1; }

  int srow[4], ksh[4];
#pragma unroll
  for (int q = 0; q < 4; ++q) {
    int s = q * 256 + t;
    int r = s >> 3, g = s & 7;
    srow[q] = r;
    ksh[q] = (g ^ (r & 7)) * 8;
  }

  int lrow = lane & 15;
  int klo = (lane >> 4) << 4;
  int sw = (lane & 7) << 4;
  int scanrow = t & 127, side = t >> 7;

  for (int tt = 0; tt < 8; ++tt) {
    int c0 = cbase + tt * 128;
    if (t < 128) sqc[t] = sqx[c0 + t];

    f32x4 acc[16] = {};

    for (int kt = 0; kt < 16; ++kt) {
      int kb = kt << 6;
#pragma unroll
      for (int q = 0; q < 4; ++q) {
        gload16(xb + (size_t)(r0 + srow[q]) * DD + kb + ksh[q], At + (q * 256 + wbase) * 8);
        gload16(xb + (size_t)(c0 + srow[q]) * DD + kb + ksh[q], Bt + (q * 256 + wbase) * 8);
      }
      __syncthreads();
#pragma unroll
      for (int kh = 0; kh < 2; ++kh) {
        int kbyte = ((kh << 6) | klo) ^ sw;
        fragT af[4], bf[4];
#pragma unroll
        for (int m = 0; m < 4; ++m)
          af[m] = *(const fragT*)((const char*)At + (wr * 64 + m * 16 + lrow) * 128 + kbyte);
#pragma unroll
        for (int n = 0; n < 4; ++n)
          bf[n] = *(const fragT*)((const char*)Bt + (wc * 64 + n * 16 + lrow) * 128 + kbyte);
#pragma unroll
        for (int m = 0; m < 4; ++m)
#pragma unroll
          for (int n = 0; n < 4; ++n)
            acc[m * 4 + n] =
                __builtin_amdgcn_mfma_f32_16x16x32_bf16(af[m], bf[n], acc[m * 4 + n], 0, 0, 0);
      }
      __syncthreads();
    }

    // epilogue: two 64-col halves through S, scan with all 256 threads
#pragma unroll
    for (int nh = 0; nh < 2; ++nh) {
      if (wc == nh) {
#pragma unroll
        for (int m = 0; m < 4; ++m) {
          int row0 = wr * 64 + m * 16 + ((lane >> 4) << 2);
          f32x4 sq4 = *(const f32x4*)&sqr[row0];
#pragma unroll
          for (int n = 0; n < 4; ++n) {
            int colL = n * 16 + lrow;           // 0..63 within half
            int gcol = c0 + nh * 64 + colL;
            float sc = sqc[nh * 64 + colL];
            f32x4 a = acc[m * 4 + n];
            f16x4 hv;
#pragma unroll
            for (int r = 0; r < 4; ++r) {
              float d2 = sq4[r] + sc - 2.f * a[r];
              if (r0 + row0 + r == gcol) d2 = 65000.f;
              hv[r] = (_Float16)d2;
            }
            *(f16x4*)((char*)S + colL * 256 + ((row0 * 2) ^ ((colL & 7) << 3))) = hv;
          }
        }
      }
      __syncthreads();
      {
        int cc0 = side * 32;
        for (int c = 0; c < 32; ++c) {
          int cl = cc0 + c;
          float d = (float)*(const _Float16*)((const char*)S + cl * 256 +
                                              ((scanrow * 2) ^ ((cl & 7) << 3)));
          if (d < ld[KNN - 1]) {
            float v = d;
            int vi = c0 + nh * 64 + cl;
#pragma unroll
            for (int p = 0; p < KNN; ++p) {
              if (v < ld[p]) {
                float tv = ld[p]; int ti = li[p];
                ld[p] = v; li[p] = vi;
                v = tv; vi = ti;
              }
            }
          }
        }
      }
      __syncthreads();
    }
  }

  // merge the two per-side lists of each row via LDS (reuse S: 128*15*8B = 15KB)
  float* Sf = (float*)S;
  int* Si = (int*)((char*)S + 128 * KNN * 4);
  if (t >= 128) {
    int r = t - 128;
#pragma unroll
    for (int p = 0; p < KNN; ++p) {
      Sf[r * KNN + p] = ld[p];
      Si[r * KNN + p] = li[p];
    }
  }
  __syncthreads();
  if (t < 128) {
#pragma unroll
    for (int p0 = 0; p0 < KNN; ++p0) {
      float v = Sf[t * KNN + p0];
      int vi = Si[t * KNN + p0];
      if (v < ld[KNN - 1]) {
#pragma unroll
        for (int p = 0; p < KNN; ++p) {
          if (v < ld[p]) {
            float tv = ld[p]; int ti = li[p];
            ld[p] = v; li[p] = vi;
            v = tv; vi = ti;
          }
        }
      }
    }
    size_t base = ((size_t)(r0 + t) * CSPLIT + cs) * KNN;
#pragma unroll
    for (int p = 0; p < KNN; ++p) {
      part_d2[base + p] = ld[p];
      part_idx[base + p] = li[p];
    }
  }
}

// ---------------- merge partial top-k, build directed bitmask, xmax ----------------
__global__ void k_merge(const float* __restrict__ part_d2, const int* __restrict__ part_idx,
                        float* __restrict__ knn_d2, int* __restrict__ knn_idx,
                        unsigned* __restrict__ Mdir, int* __restrict__ xmax_bits) {
  int i = blockIdx.x * 256 + threadIdx.x;
  float ld[KNN];
  int li[KNN];
#pragma unroll
  for (int p = 0; p < KNN; ++p) { ld[p] = 3.0e38f; li[p] = -1; }
  size_t base = (size_t)i * CSPLIT * KNN;
  for (int q = 0; q < CSPLIT * KNN; ++q) {
    float d = part_d2[base + q];
    int idx = part_idx[base + q];
    if (d < ld[KNN - 1]) {
      float v = d; int vi = idx;
#pragma unroll
      for (int p = 0; p < KNN; ++p) {
        if (v < ld[p]) {
          float tv = ld[p]; int ti = li[p];
          ld[p] = v; li[p] = vi;
          v = tv; vi = ti;
        }
      }
    }
  }
  float mx = 0.f;
#pragma unroll
  for (int p = 0; p < KNN; ++p) {
    float d = fmaxf(ld[p], 0.f);
    mx = fmaxf(mx, d);
    knn_d2[(size_t)i * KNN + p] = d;
    int j = li[p];
    knn_idx[(size_t)i * KNN + p] = j;
    atomicOr(&Mdir[(size_t)i * (BB / 32) + (j >> 5)], 1u << (j & 31));
  }
  atomicMax(xmax_bits, __float_as_int(mx));
}

// ---------------- per-edge z distances (exact fp32) + zmax ----------------
__global__ void k_edge_z(const float* __restrict__ z, const int* __restrict__ knn_idx,
                         float* __restrict__ zd2, int* __restrict__ zmax_bits) {
  int e = blockIdx.x * 4 + (threadIdx.x >> 6);
  int lane = threadIdx.x & 63;
  int i = e / KNN;
  int j = knn_idx[e];
  float zi = z[(size_t)i * LL + lane];
  float zj = z[(size_t)j * LL + lane];
  float d = zi - zj;
  float v = d * d;
#pragma unroll
  for (int off = 32; off >= 1; off >>= 1) v += __shfl_down(v, off);
  if (lane == 0) {
    zd2[e] = v;
    atomicMax(zmax_bits, __float_as_int(v));
  }
}

// ---------------- edge loss accumulation ----------------
__global__ void k_loss(const float* __restrict__ knn_d2, const int* __restrict__ knn_idx,
                       const float* __restrict__ zd2, const unsigned* __restrict__ Mdir,
                       const int* __restrict__ xmax_bits, const int* __restrict__ zmax_bits,
                       float* __restrict__ loss_sum, float* __restrict__ cnt_sum) {
  int e = blockIdx.x * 256 + threadIdx.x;
  float inv_x = 1.f / (sqrtf(__int_as_float(*xmax_bits)) + 1e-8f);
  float inv_z = 1.f / (sqrtf(__int_as_float(*zmax_bits)) + 1e-8f);
  int i = e / KNN;
  int j = knn_idx[e];
  unsigned bit = (Mdir[(size_t)j * (BB / 32) + (i >> 5)] >> (i & 31)) & 1u;
  float wgt = bit ? 1.f : 2.f;  // reciprocal edge counted once each direction
  float xd = sqrtf(knn_d2[e]);
  float zd = sqrtf(fmaxf(zd2[e], 0.f));
  float diff = zd * inv_z - xd * inv_x;
  float c1 = wgt * diff * diff;
  float c2 = wgt;
#pragma unroll
  for (int off = 32; off >= 1; off >>= 1) {
    c1 += __shfl_down(c1, off);
    c2 += __shfl_down(c2, off);
  }
  __shared__ float r1[4], r2[4];
  int t = threadIdx.x;
  if ((t & 63) == 0) { r1[t >> 6] = c1; r2[t >> 6] = c2; }
  __syncthreads();
  if (t == 0) {
    atomicAdd(loss_sum, r1[0] + r1[1] + r1[2] + r1[3]);
    atomicAdd(cnt_sum, r2[0] + r2[1] + r2[2] + r2[3]);
  }
}

__global__ void k_final(const float* __restrict__ rec_sum, const float* __restrict__ loss_sum,
                        const float* __restrict__ cnt_sum, float* __restrict__ out) {
  if (threadIdx.x == 0)
    out[0] = rec_sum[0] * (1.f / 8388608.f) + loss_sum[0] / cnt_sum[0];
}

extern "C" void kernel_launch(void* const* d_in, const int* in_sizes, int n_in,
                              void* d_out, int out_size, void* d_ws, size_t ws_size,
                              hipStream_t stream) {
  const float* x = (const float*)d_in[0];
  const float* We1 = (const float*)d_in[1];
  const float* be1 = (const float*)d_in[2];
  const float* We2 = (const float*)d_in[3];
  const float* be2 = (const float*)d_in[4];
  const float* Wd1 = (const float*)d_in[5];
  const float* bd1 = (const float*)d_in[6];
  const float* Wd2 = (const float*)d_in[7];
  const float* bd2 = (const float*)d_in[8];

  char* ws = (char*)d_ws;
  size_t off = 0;
  auto alloc = [&](size_t bytes) {
    void* p = ws + off;
    off += (bytes + 255) & ~(size_t)255;
    return p;
  };
  unsigned short* xb = (unsigned short*)alloc((size_t)BB * DD * 2);
  unsigned short* hb = (unsigned short*)alloc((size_t)BB * HH * 2);
  unsigned short* zb = (unsigned short*)alloc((size_t)BB * LL * 2);
  unsigned short* h2b = (unsigned short*)alloc((size_t)BB * HH * 2);
  float* z = (float*)alloc((size_t)BB * LL * 4);
  float* sqx = (float*)alloc((size_t)BB * 4);
  unsigned short* Wt1 = (unsigned short*)alloc((size_t)HH * DD * 2);
  unsigned short* Wt2 = (unsigned short*)alloc((size_t)LL * HH * 2);
  unsigned short* Wt3 = (unsigned short*)alloc((size_t)HH * LL * 2);
  unsigned short* Wt4 = (unsigned short*)alloc((size_t)DD * HH * 2);
  float* part_d2 = (float*)alloc((size_t)BB * CSPLIT * KNN * 4);
  int* part_idx = (int*)alloc((size_t)BB * CSPLIT * KNN * 4);
  float* knn_d2 = (float*)alloc((size_t)BB * KNN * 4);
  int* knn_idx = (int*)alloc((size_t)BB * KNN * 4);
  float* zd2 = (float*)alloc((size_t)BB * KNN * 4);
  unsigned* Mdir = (unsigned*)alloc((size_t)BB * (BB / 32) * 4);
  float* scal = (float*)alloc(64);
  float* rec_sum = scal + 0;
  float* loss_sum = scal + 1;
  float* cnt_sum = scal + 2;
  int* xmax_bits = (int*)(scal + 3);
  int* zmax_bits = (int*)(scal + 4);

  hipMemsetAsync(Mdir, 0, (size_t)BB * (BB / 32) * 4, stream);
  hipMemsetAsync(scal, 0, 64, stream);

  k_convert<<<BB, 256, 0, stream>>>(x, xb, sqx);
  k_wt<<<dim3(DD / 64, HH / 64), 256, 0, stream>>>(We1, Wt1, DD, HH);
  k_wt<<<dim3(HH / 64, LL / 64), 256, 0, stream>>>(We2, Wt2, HH, LL);
  k_wt<<<dim3(LL / 64, HH / 64), 256, 0, stream>>>(Wd1, Wt3, LL, HH);
  k_wt<<<dim3(HH / 64, DD / 64), 256, 0, stream>>>(Wd2, Wt4, HH, DD);

  k_gram_topk<<<(BB / 128) * CSPLIT, 256, 0, stream>>>(xb, sqx, part_d2, part_idx);

  // G1: h = relu(x @ We1 + be1)  (bf16 out)
  k_mgemm<4, 1, 0, 0, 1><<<dim3(HH / 128, BB / 128), 256, 0, stream>>>(
      xb, Wt1, be1, hb, nullptr, nullptr, nullptr, HH, DD);
  // G2: z = h @ We2 + be2  (f32 + bf16 out)
  k_mgemm<2, 0, 0, 1, 1><<<dim3(LL / 64, BB / 128), 256, 0, stream>>>(
      hb, Wt2, be2, zb, z, nullptr, nullptr, LL, HH);
  // G3: h2 = relu(z @ Wd1 + bd1)  (bf16 out)
  k_mgemm<4, 1, 0, 0, 1><<<dim3(HH / 128, BB / 128), 256, 0, stream>>>(
      zb, Wt3, bd1, h2b, nullptr, nullptr, nullptr, HH, LL);
  // G4: rec_sum += sum((h2 @ Wd2 + bd2 - x)^2)
  k_mgemm<4, 0, 1, 0, 0><<<dim3(DD / 128, BB / 128), 256, 0, stream>>>(
      h2b, Wt4, bd2, nullptr, nullptr, x, rec_sum, DD, HH);

  k_merge<<<BB / 256, 256, 0, stream>>>(part_d2, part_idx, knn_d2, knn_idx, Mdir, xmax_bits);
  k_edge_z<<<NEDGE / 4, 256, 0, stream>>>(z, knn_idx, zd2, zmax_bits);
  k_loss<<<NEDGE / 256, 256, 0, stream>>>(knn_d2, knn_idx, zd2, Mdir, xmax_bits, zmax_bits,
                                          loss_sum, cnt_sum);
  k_final<<<1, 64, 0, stream>>>(rec_sum, loss_sum, cnt_sum, (float*)d_out);
}

// Round 4
// 1494.585 us; speedup vs baseline: 2.4414x; 1.9332x over previous
//
#include <hip/hip_runtime.h>

#define BB 8192
#define DD 1024
#define HH 512
#define LL 64
#define KNN 15
#define CSPLIT 8
#define NEDGE (BB * KNN)

typedef __attribute__((ext_vector_type(4))) float f32x4;
typedef __attribute__((ext_vector_type(8))) short s16x8;
typedef __attribute__((ext_vector_type(8))) unsigned short u16x8;
typedef __attribute__((ext_vector_type(4))) unsigned short u16x4;
typedef __attribute__((ext_vector_type(4))) _Float16 f16x4;

typedef s16x8 fragT;

__device__ __forceinline__ unsigned short f2bf(float f) {
  unsigned u = __float_as_uint(f);
  return (unsigned short)((u + 0x7fffu + ((u >> 16) & 1u)) >> 16);  // RNE
}

__device__ __forceinline__ void gload16(const void* g, void* l) {
  __builtin_amdgcn_global_load_lds((const __attribute__((address_space(1))) unsigned int*)g,
                                   (__attribute__((address_space(3))) unsigned int*)l, 16, 0, 0);
}

// ---------------- convert x -> bf16 + row norms ----------------
__global__ void k_convert(const float* __restrict__ x, unsigned short* __restrict__ xb,
                          float* __restrict__ sqx) {
  int row = blockIdx.x;
  int t = threadIdx.x;
  f32x4 v = *(const f32x4*)(x + (size_t)row * DD + t * 4);
  u16x4 o;
  float s = 0.f;
#pragma unroll
  for (int j = 0; j < 4; ++j) {
    float f = v[j];
    s += f * f;
    o[j] = f2bf(f);
  }
  *(u16x4*)(xb + (size_t)row * DD + t * 4) = o;
#pragma unroll
  for (int off = 32; off >= 1; off >>= 1) s += __shfl_down(s, off);
  __shared__ float ps[4];
  if ((t & 63) == 0) ps[t >> 6] = s;
  __syncthreads();
  if (t == 0) sqx[row] = ps[0] + ps[1] + ps[2] + ps[3];
}

// ---------------- weight transpose+convert: W (K x N) f32 -> Wt (N x K) bf16 ----------------
__global__ void k_wt(const float* __restrict__ W, unsigned short* __restrict__ Wt, int Kd, int N) {
  __shared__ unsigned short T[64][65];
  int k0 = blockIdx.x * 64, n0 = blockIdx.y * 64;
  int t = threadIdx.x;
  int kr = t >> 4, nc = (t & 15) * 4;
#pragma unroll
  for (int q = 0; q < 4; ++q) {
    int k = kr + q * 16;
    f32x4 v = *(const f32x4*)(W + (size_t)(k0 + k) * N + n0 + nc);
#pragma unroll
    for (int j = 0; j < 4; ++j) T[nc + j][k] = f2bf(v[j]);
  }
  __syncthreads();
#pragma unroll
  for (int q = 0; q < 2; ++q) {
    int s = t + q * 256;
    int n = s >> 3, c = (s & 7) * 8;
    u16x8 o;
#pragma unroll
    for (int j = 0; j < 8; ++j) o[j] = T[n][c + j];
    *(u16x8*)(Wt + (size_t)(n0 + n) * Kd + k0 + c) = o;
  }
}

// ---------------- bf16 MFMA GEMM: C = act(A @ Wt^T + bias) ----------------
template <int NF, int RELU, int FUSE, int STF32, int STBF>
__global__ __launch_bounds__(256) void k_mgemm(
    const unsigned short* __restrict__ A, const unsigned short* __restrict__ Wt,
    const float* __restrict__ bias, unsigned short* __restrict__ Cb, float* __restrict__ Cf,
    const float* __restrict__ Xref, float* __restrict__ rec_sum, int N, int Kd) {
  __shared__ __attribute__((aligned(16))) unsigned short At[128 * 64];
  __shared__ __attribute__((aligned(16))) unsigned short Bt[NF * 32 * 64];
  int t = threadIdx.x;
  int lane = t & 63, w = t >> 6;
  int wr = w >> 1, wc = w & 1;
  int wbase = w * 64;
  int m0 = blockIdx.y * 128, n0 = blockIdx.x * (NF * 32);

  int srow[4], ksh[4];
#pragma unroll
  for (int q = 0; q < 4; ++q) {
    int s = q * 256 + t;
    int r = s >> 3, g = s & 7;
    srow[q] = r;
    ksh[q] = (g ^ (r & 7)) * 8;  // shorts
  }

  int lrow = lane & 15;
  int klo = (lane >> 4) << 4;
  int sw = (lane & 7) << 4;

  f32x4 acc[4][NF] = {};

  int ksteps = Kd >> 6;
  for (int kt = 0; kt < ksteps; ++kt) {
    int kb = kt << 6;
#pragma unroll
    for (int q = 0; q < 4; ++q)
      gload16(A + (size_t)(m0 + srow[q]) * Kd + kb + ksh[q], At + (q * 256 + wbase) * 8);
#pragma unroll
    for (int q = 0; q < NF; ++q)
      gload16(Wt + (size_t)(n0 + srow[q]) * Kd + kb + ksh[q], Bt + (q * 256 + wbase) * 8);
    __syncthreads();
#pragma unroll
    for (int kh = 0; kh < 2; ++kh) {
      int kbyte = ((kh << 6) | klo) ^ sw;
      fragT af[4], bf[NF];
#pragma unroll
      for (int m = 0; m < 4; ++m)
        af[m] = *(const fragT*)((const char*)At + (wr * 64 + m * 16 + lrow) * 128 + kbyte);
#pragma unroll
      for (int n = 0; n < NF; ++n)
        bf[n] = *(const fragT*)((const char*)Bt + (wc * NF * 16 + n * 16 + lrow) * 128 + kbyte);
#pragma unroll
      for (int m = 0; m < 4; ++m)
#pragma unroll
        for (int n = 0; n < NF; ++n)
          acc[m][n] = __builtin_amdgcn_mfma_f32_16x16x32_bf16(af[m], bf[n], acc[m][n], 0, 0, 0);
    }
    __syncthreads();
  }

  float local = 0.f;
#pragma unroll
  for (int m = 0; m < 4; ++m) {
    int row0 = m0 + wr * 64 + m * 16 + ((lane >> 4) << 2);
#pragma unroll
    for (int n = 0; n < NF; ++n) {
      int col = n0 + wc * NF * 16 + n * 16 + lrow;
      float bv = bias[col];
      f32x4 a = acc[m][n];
#pragma unroll
      for (int j = 0; j < 4; ++j) {
        float c = a[j] + bv;
        if (RELU) c = fmaxf(c, 0.f);
        if (FUSE) {
          float xv = Xref[(size_t)(row0 + j) * N + col];
          float d = c - xv;
          local = fmaf(d, d, local);
        }
        if (STBF) Cb[(size_t)(row0 + j) * N + col] = f2bf(c);
        if (STF32) Cf[(size_t)(row0 + j) * N + col] = c;
      }
    }
  }
  if (FUSE) {
#pragma unroll
    for (int off = 32; off >= 1; off >>= 1) local += __shfl_down(local, off);
    __shared__ float rs[4];
    if ((t & 63) == 0) rs[t >> 6] = local;
    __syncthreads();
    if (t == 0) atomicAdd(rec_sum, rs[0] + rs[1] + rs[2] + rs[3]);
  }
}

// ---------------- Gram (bf16 MFMA) + fused per-row top-15 ----------------
__global__ __launch_bounds__(256) void k_gram_topk(
    const unsigned short* __restrict__ xb, const float* __restrict__ sqx,
    float* __restrict__ part_d2, int* __restrict__ part_idx) {
  __shared__ __attribute__((aligned(16))) unsigned short At[128 * 64];  // 16KB
  __shared__ __attribute__((aligned(16))) unsigned short Bt[128 * 64];  // 16KB
  __shared__ __attribute__((aligned(16))) _Float16 S[64 * 128];         // 16KB [col 64][row 128]
  __shared__ float sqr[128], sqc[128];

  int bid = blockIdx.x;
  int rt = bid >> 3, cs = bid & 7;
  int r0 = rt * 128, cbase = cs * 1024;
  int t = threadIdx.x;
  int lane = t & 63, w = t >> 6;
  int wr = w >> 1, wc = w & 1;
  int wbase = w * 64;

  if (t < 128) sqr[t] = sqx[r0 + t];

  float ld[KNN];
  int li[KNN];
#pragma unroll
  for (int p = 0; p < KNN; ++p) { ld[p] = 3.0e38f; li[p] = -1; }

  int srow[4], ksh[4];
#pragma unroll
  for (int q = 0; q < 4; ++q) {
    int s = q * 256 + t;
    int r = s >> 3, g = s & 7;
    srow[q] = r;
    ksh[q] = (g ^ (r & 7)) * 8;
  }

  int lrow = lane & 15;
  int klo = (lane >> 4) << 4;
  int sw = (lane & 7) << 4;
  int scanrow = t & 127, side = t >> 7;

  for (int tt = 0; tt < 8; ++tt) {
    int c0 = cbase + tt * 128;
    if (t < 128) sqc[t] = sqx[c0 + t];

    f32x4 acc[16] = {};

    for (int kt = 0; kt < 16; ++kt) {
      int kb = kt << 6;
#pragma unroll
      for (int q = 0; q < 4; ++q) {
        gload16(xb + (size_t)(r0 + srow[q]) * DD + kb + ksh[q], At + (q * 256 + wbase) * 8);
        gload16(xb + (size_t)(c0 + srow[q]) * DD + kb + ksh[q], Bt + (q * 256 + wbase) * 8);
      }
      __syncthreads();
#pragma unroll
      for (int kh = 0; kh < 2; ++kh) {
        int kbyte = ((kh << 6) | klo) ^ sw;
        fragT af[4], bf[4];
#pragma unroll
        for (int m = 0; m < 4; ++m)
          af[m] = *(const fragT*)((const char*)At + (wr * 64 + m * 16 + lrow) * 128 + kbyte);
#pragma unroll
        for (int n = 0; n < 4; ++n)
          bf[n] = *(const fragT*)((const char*)Bt + (wc * 64 + n * 16 + lrow) * 128 + kbyte);
#pragma unroll
        for (int m = 0; m < 4; ++m)
#pragma unroll
          for (int n = 0; n < 4; ++n)
            acc[m * 4 + n] =
                __builtin_amdgcn_mfma_f32_16x16x32_bf16(af[m], bf[n], acc[m * 4 + n], 0, 0, 0);
      }
      __syncthreads();
    }

#pragma unroll
    for (int nh = 0; nh < 2; ++nh) {
      if (wc == nh) {
#pragma unroll
        for (int m = 0; m < 4; ++m) {
          int row0 = wr * 64 + m * 16 + ((lane >> 4) << 2);
          f32x4 sq4 = *(const f32x4*)&sqr[row0];
#pragma unroll
          for (int n = 0; n < 4; ++n) {
            int colL = n * 16 + lrow;
            int gcol = c0 + nh * 64 + colL;
            float sc = sqc[nh * 64 + colL];
            f32x4 a = acc[m * 4 + n];
            f16x4 hv;
#pragma unroll
            for (int r = 0; r < 4; ++r) {
              float d2 = sq4[r] + sc - 2.f * a[r];
              if (r0 + row0 + r == gcol) d2 = 65000.f;
              hv[r] = (_Float16)d2;
            }
            *(f16x4*)((char*)S + colL * 256 + ((row0 * 2) ^ ((colL & 7) << 3))) = hv;
          }
        }
      }
      __syncthreads();
      {
        int cc0 = side * 32;
        for (int c = 0; c < 32; ++c) {
          int cl = cc0 + c;
          float d = (float)*(const _Float16*)((const char*)S + cl * 256 +
                                              ((scanrow * 2) ^ ((cl & 7) << 3)));
          if (d < ld[KNN - 1]) {
            float v = d;
            int vi = c0 + nh * 64 + cl;
#pragma unroll
            for (int p = 0; p < KNN; ++p) {
              if (v < ld[p]) {
                float tv = ld[p]; int ti = li[p];
                ld[p] = v; li[p] = vi;
                v = tv; vi = ti;
              }
            }
          }
        }
      }
      __syncthreads();
    }
  }

  float* Sf = (float*)S;
  int* Si = (int*)((char*)S + 128 * KNN * 4);
  if (t >= 128) {
    int r = t - 128;
#pragma unroll
    for (int p = 0; p < KNN; ++p) {
      Sf[r * KNN + p] = ld[p];
      Si[r * KNN + p] = li[p];
    }
  }
  __syncthreads();
  if (t < 128) {
#pragma unroll
    for (int p0 = 0; p0 < KNN; ++p0) {
      float v = Sf[t * KNN + p0];
      int vi = Si[t * KNN + p0];
      if (v < ld[KNN - 1]) {
#pragma unroll
        for (int p = 0; p < KNN; ++p) {
          if (v < ld[p]) {
            float tv = ld[p]; int ti = li[p];
            ld[p] = v; li[p] = vi;
            v = tv; vi = ti;
          }
        }
      }
    }
    size_t base = ((size_t)(r0 + t) * CSPLIT + cs) * KNN;
#pragma unroll
    for (int p = 0; p < KNN; ++p) {
      part_d2[base + p] = ld[p];
      part_idx[base + p] = li[p];
    }
  }
}

// ---------------- merge partial top-k, build directed bitmask, xmax ----------------
__global__ void k_merge(const float* __restrict__ part_d2, const int* __restrict__ part_idx,
                        float* __restrict__ knn_d2, int* __restrict__ knn_idx,
                        unsigned* __restrict__ Mdir, int* __restrict__ xmax_bits) {
  int i = blockIdx.x * 256 + threadIdx.x;
  float ld[KNN];
  int li[KNN];
#pragma unroll
  for (int p = 0; p < KNN; ++p) { ld[p] = 3.0e38f; li[p] = -1; }
  size_t base = (size_t)i * CSPLIT * KNN;
  for (int q = 0; q < CSPLIT * KNN; ++q) {
    float d = part_d2[base + q];
    int idx = part_idx[base + q];
    if (d < ld[KNN - 1]) {
      float v = d; int vi = idx;
#pragma unroll
      for (int p = 0; p < KNN; ++p) {
        if (v < ld[p]) {
          float tv = ld[p]; int ti = li[p];
          ld[p] = v; li[p] = vi;
          v = tv; vi = ti;
        }
      }
    }
  }
  float mx = 0.f;
#pragma unroll
  for (int p = 0; p < KNN; ++p) {
    float d = fmaxf(ld[p], 0.f);
    mx = fmaxf(mx, d);
    knn_d2[(size_t)i * KNN + p] = d;
    int j = li[p];
    knn_idx[(size_t)i * KNN + p] = j;
    atomicOr(&Mdir[(size_t)i * (BB / 32) + (j >> 5)], 1u << (j & 31));
  }
  // block-level max then one atomic
  int t = threadIdx.x;
#pragma unroll
  for (int off = 32; off >= 1; off >>= 1) mx = fmaxf(mx, __shfl_down(mx, off));
  __shared__ float rm[4];
  if ((t & 63) == 0) rm[t >> 6] = mx;
  __syncthreads();
  if (t == 0) {
    float m = fmaxf(fmaxf(rm[0], rm[1]), fmaxf(rm[2], rm[3]));
    atomicMax(xmax_bits, __float_as_int(m));
  }
}

// ---------------- per-edge z distances (exact fp32), no atomics ----------------
__global__ void k_edge_z(const float* __restrict__ z, const int* __restrict__ knn_idx,
                         float* __restrict__ zd2) {
  int e = blockIdx.x * 4 + (threadIdx.x >> 6);
  int lane = threadIdx.x & 63;
  int i = e / KNN;
  int j = knn_idx[e];
  float zi = z[(size_t)i * LL + lane];
  float zj = z[(size_t)j * LL + lane];
  float d = zi - zj;
  float v = d * d;
#pragma unroll
  for (int off = 32; off >= 1; off >>= 1) v += __shfl_down(v, off);
  if (lane == 0) zd2[e] = v;
}

// ---------------- zmax reduce: one atomic per block ----------------
__global__ void k_zmax(const float* __restrict__ zd2, int* __restrict__ zmax_bits) {
  int t = threadIdx.x;
  int idx = blockIdx.x * 256 + t;
  float mx = 0.f;
  for (int e = idx; e < NEDGE; e += 120 * 256) mx = fmaxf(mx, zd2[e]);
#pragma unroll
  for (int off = 32; off >= 1; off >>= 1) mx = fmaxf(mx, __shfl_down(mx, off));
  __shared__ float rm[4];
  if ((t & 63) == 0) rm[t >> 6] = mx;
  __syncthreads();
  if (t == 0) {
    float m = fmaxf(fmaxf(rm[0], rm[1]), fmaxf(rm[2], rm[3]));
    atomicMax(zmax_bits, __float_as_int(m));
  }
}

// ---------------- edge loss accumulation ----------------
__global__ void k_loss(const float* __restrict__ knn_d2, const int* __restrict__ knn_idx,
                       const float* __restrict__ zd2, const unsigned* __restrict__ Mdir,
                       const int* __restrict__ xmax_bits, const int* __restrict__ zmax_bits,
                       float* __restrict__ loss_sum, float* __restrict__ cnt_sum) {
  int e = blockIdx.x * 256 + threadIdx.x;
  float inv_x = 1.f / (sqrtf(__int_as_float(*xmax_bits)) + 1e-8f);
  float inv_z = 1.f / (sqrtf(__int_as_float(*zmax_bits)) + 1e-8f);
  int i = e / KNN;
  int j = knn_idx[e];
  unsigned bit = (Mdir[(size_t)j * (BB / 32) + (i >> 5)] >> (i & 31)) & 1u;
  float wgt = bit ? 1.f : 2.f;
  float xd = sqrtf(knn_d2[e]);
  float zd = sqrtf(fmaxf(zd2[e], 0.f));
  float diff = zd * inv_z - xd * inv_x;
  float c1 = wgt * diff * diff;
  float c2 = wgt;
#pragma unroll
  for (int off = 32; off >= 1; off >>= 1) {
    c1 += __shfl_down(c1, off);
    c2 += __shfl_down(c2, off);
  }
  __shared__ float r1[4], r2[4];
  int t = threadIdx.x;
  if ((t & 63) == 0) { r1[t >> 6] = c1; r2[t >> 6] = c2; }
  __syncthreads();
  if (t == 0) {
    atomicAdd(loss_sum, r1[0] + r1[1] + r1[2] + r1[3]);
    atomicAdd(cnt_sum, r2[0] + r2[1] + r2[2] + r2[3]);
  }
}

__global__ void k_final(const float* __restrict__ rec_sum, const float* __restrict__ loss_sum,
                        const float* __restrict__ cnt_sum, float* __restrict__ out) {
  if (threadIdx.x == 0)
    out[0] = rec_sum[0] * (1.f / 8388608.f) + loss_sum[0] / cnt_sum[0];
}

extern "C" void kernel_launch(void* const* d_in, const int* in_sizes, int n_in,
                              void* d_out, int out_size, void* d_ws, size_t ws_size,
                              hipStream_t stream) {
  const float* x = (const float*)d_in[0];
  const float* We1 = (const float*)d_in[1];
  const float* be1 = (const float*)d_in[2];
  const float* We2 = (const float*)d_in[3];
  const float* be2 = (const float*)d_in[4];
  const float* Wd1 = (const float*)d_in[5];
  const float* bd1 = (const float*)d_in[6];
  const float* Wd2 = (const float*)d_in[7];
  const float* bd2 = (const float*)d_in[8];

  char* ws = (char*)d_ws;
  size_t off = 0;
  auto alloc = [&](size_t bytes) {
    void* p = ws + off;
    off += (bytes + 255) & ~(size_t)255;
    return p;
  };
  unsigned short* xb = (unsigned short*)alloc((size_t)BB * DD * 2);
  unsigned short* hb = (unsigned short*)alloc((size_t)BB * HH * 2);
  unsigned short* zb = (unsigned short*)alloc((size_t)BB * LL * 2);
  unsigned short* h2b = (unsigned short*)alloc((size_t)BB * HH * 2);
  float* z = (float*)alloc((size_t)BB * LL * 4);
  float* sqx = (float*)alloc((size_t)BB * 4);
  unsigned short* Wt1 = (unsigned short*)alloc((size_t)HH * DD * 2);
  unsigned short* Wt2 = (unsigned short*)alloc((size_t)LL * HH * 2);
  unsigned short* Wt3 = (unsigned short*)alloc((size_t)HH * LL * 2);
  unsigned short* Wt4 = (unsigned short*)alloc((size_t)DD * HH * 2);
  float* part_d2 = (float*)alloc((size_t)BB * CSPLIT * KNN * 4);
  int* part_idx = (int*)alloc((size_t)BB * CSPLIT * KNN * 4);
  float* knn_d2 = (float*)alloc((size_t)BB * KNN * 4);
  int* knn_idx = (int*)alloc((size_t)BB * KNN * 4);
  float* zd2 = (float*)alloc((size_t)BB * KNN * 4);
  unsigned* Mdir = (unsigned*)alloc((size_t)BB * (BB / 32) * 4);
  float* scal = (float*)alloc(64);
  float* rec_sum = scal + 0;
  float* loss_sum = scal + 1;
  float* cnt_sum = scal + 2;
  int* xmax_bits = (int*)(scal + 3);
  int* zmax_bits = (int*)(scal + 4);

  hipMemsetAsync(Mdir, 0, (size_t)BB * (BB / 32) * 4, stream);
  hipMemsetAsync(scal, 0, 64, stream);

  k_convert<<<BB, 256, 0, stream>>>(x, xb, sqx);
  k_wt<<<dim3(DD / 64, HH / 64), 256, 0, stream>>>(We1, Wt1, DD, HH);
  k_wt<<<dim3(HH / 64, LL / 64), 256, 0, stream>>>(We2, Wt2, HH, LL);
  k_wt<<<dim3(LL / 64, HH / 64), 256, 0, stream>>>(Wd1, Wt3, LL, HH);
  k_wt<<<dim3(HH / 64, DD / 64), 256, 0, stream>>>(Wd2, Wt4, HH, DD);

  k_gram_topk<<<(BB / 128) * CSPLIT, 256, 0, stream>>>(xb, sqx, part_d2, part_idx);

  k_mgemm<4, 1, 0, 0, 1><<<dim3(HH / 128, BB / 128), 256, 0, stream>>>(
      xb, Wt1, be1, hb, nullptr, nullptr, nullptr, HH, DD);
  k_mgemm<2, 0, 0, 1, 1><<<dim3(LL / 64, BB / 128), 256, 0, stream>>>(
      hb, Wt2, be2, zb, z, nullptr, nullptr, LL, HH);
  k_mgemm<4, 1, 0, 0, 1><<<dim3(HH / 128, BB / 128), 256, 0, stream>>>(
      zb, Wt3, bd1, h2b, nullptr, nullptr, nullptr, HH, LL);
  k_mgemm<4, 0, 1, 0, 0><<<dim3(DD / 128, BB / 128), 256, 0, stream>>>(
      h2b, Wt4, bd2, nullptr, nullptr, x, rec_sum, DD, HH);

  k_merge<<<BB / 256, 256, 0, stream>>>(part_d2, part_idx, knn_d2, knn_idx, Mdir, xmax_bits);
  k_edge_z<<<NEDGE / 4, 256, 0, stream>>>(z, knn_idx, zd2);
  k_zmax<<<120, 256, 0, stream>>>(zd2, zmax_bits);
  k_loss<<<NEDGE / 256, 256, 0, stream>>>(knn_d2, knn_idx, zd2, Mdir, xmax_bits, zmax_bits,
                                          loss_sum, cnt_sum);
  k_final<<<1, 64, 0, stream>>>(rec_sum, loss_sum, cnt_sum, (float*)d_out);
}

// Round 5
// 493.837 us; speedup vs baseline: 7.3888x; 3.0265x over previous
//
#include <hip/hip_runtime.h>

#define BB 8192
#define DD 1024
#define HH 512
#define LL 64
#define KNN 15
#define NT 64            // 8192/128 tiles per dim
#define NTILES 2080      // NT*(NT+1)/2
#define NEDGE (BB * KNN)

typedef __attribute__((ext_vector_type(4))) float f32x4;
typedef __attribute__((ext_vector_type(8))) short s16x8;
typedef __attribute__((ext_vector_type(8))) unsigned short u16x8;
typedef __attribute__((ext_vector_type(4))) unsigned short u16x4;

typedef s16x8 fragT;

__device__ __forceinline__ unsigned short f2bf(float f) {
  unsigned u = __float_as_uint(f);
  return (unsigned short)((u + 0x7fffu + ((u >> 16) & 1u)) >> 16);  // RNE
}

__device__ __forceinline__ void gload16(const void* g, void* l) {
  __builtin_amdgcn_global_load_lds((const __attribute__((address_space(1))) unsigned int*)g,
                                   (__attribute__((address_space(3))) unsigned int*)l, 16, 0, 0);
}

// packed candidate: f16(d2) in high 16 bits (monotonic for d2>=0), idx in low 16
__device__ __forceinline__ unsigned packu(float d2, int idx) {
  unsigned short hb = __builtin_bit_cast(unsigned short, (_Float16)d2);
  return ((unsigned)hb << 16) | (unsigned)idx;
}

__device__ __forceinline__ float unpack_d2(unsigned u) {
  _Float16 h = __builtin_bit_cast(_Float16, (unsigned short)(u >> 16));
  return (float)h;
}

// sorted ascending top-15 insert via min/max network
__device__ __forceinline__ void ins15(unsigned (&l)[KNN], unsigned u) {
  if (u < l[KNN - 1]) {
    unsigned v = u;
#pragma unroll
    for (int p = 0; p < KNN; ++p) {
      unsigned lo = min(v, l[p]);
      unsigned hi = max(v, l[p]);
      l[p] = lo;
      v = hi;
    }
  }
}

// ---------------- convert x -> bf16 + row norms ----------------
__global__ void k_convert(const float* __restrict__ x, unsigned short* __restrict__ xb,
                          float* __restrict__ sqx) {
  int row = blockIdx.x;
  int t = threadIdx.x;
  f32x4 v = *(const f32x4*)(x + (size_t)row * DD + t * 4);
  u16x4 o;
  float s = 0.f;
#pragma unroll
  for (int j = 0; j < 4; ++j) {
    float f = v[j];
    s += f * f;
    o[j] = f2bf(f);
  }
  *(u16x4*)(xb + (size_t)row * DD + t * 4) = o;
#pragma unroll
  for (int off = 32; off >= 1; off >>= 1) s += __shfl_down(s, off);
  __shared__ float ps[4];
  if ((t & 63) == 0) ps[t >> 6] = s;
  __syncthreads();
  if (t == 0) sqx[row] = ps[0] + ps[1] + ps[2] + ps[3];
}

// ---------------- weight transpose+convert ----------------
__global__ void k_wt(const float* __restrict__ W, unsigned short* __restrict__ Wt, int Kd, int N) {
  __shared__ unsigned short T[64][65];
  int k0 = blockIdx.x * 64, n0 = blockIdx.y * 64;
  int t = threadIdx.x;
  int kr = t >> 4, nc = (t & 15) * 4;
#pragma unroll
  for (int q = 0; q < 4; ++q) {
    int k = kr + q * 16;
    f32x4 v = *(const f32x4*)(W + (size_t)(k0 + k) * N + n0 + nc);
#pragma unroll
    for (int j = 0; j < 4; ++j) T[nc + j][k] = f2bf(v[j]);
  }
  __syncthreads();
#pragma unroll
  for (int q = 0; q < 2; ++q) {
    int s = t + q * 256;
    int n = s >> 3, c = (s & 7) * 8;
    u16x8 o;
#pragma unroll
    for (int j = 0; j < 8; ++j) o[j] = T[n][c + j];
    *(u16x8*)(Wt + (size_t)(n0 + n) * Kd + k0 + c) = o;
  }
}

// ---------------- bf16 MFMA GEMM ----------------
template <int NF, int RELU, int FUSE, int STF32, int STBF>
__global__ __launch_bounds__(256) void k_mgemm(
    const unsigned short* __restrict__ A, const unsigned short* __restrict__ Wt,
    const float* __restrict__ bias, unsigned short* __restrict__ Cb, float* __restrict__ Cf,
    const float* __restrict__ Xref, float* __restrict__ rec_sum, int N, int Kd) {
  __shared__ __attribute__((aligned(16))) unsigned short At[128 * 64];
  __shared__ __attribute__((aligned(16))) unsigned short Bt[NF * 32 * 64];
  int t = threadIdx.x;
  int lane = t & 63, w = t >> 6;
  int wr = w >> 1, wc = w & 1;
  int wbase = w * 64;
  int m0 = blockIdx.y * 128, n0 = blockIdx.x * (NF * 32);

  int srow[4], ksh[4];
#pragma unroll
  for (int q = 0; q < 4; ++q) {
    int s = q * 256 + t;
    int r = s >> 3, g = s & 7;
    srow[q] = r;
    ksh[q] = (g ^ (r & 7)) * 8;
  }

  int lrow = lane & 15;
  int klo = (lane >> 4) << 4;
  int sw = (lane & 7) << 4;

  f32x4 acc[4][NF] = {};

  int ksteps = Kd >> 6;
  for (int kt = 0; kt < ksteps; ++kt) {
    int kb = kt << 6;
#pragma unroll
    for (int q = 0; q < 4; ++q)
      gload16(A + (size_t)(m0 + srow[q]) * Kd + kb + ksh[q], At + (q * 256 + wbase) * 8);
#pragma unroll
    for (int q = 0; q < NF; ++q)
      gload16(Wt + (size_t)(n0 + srow[q]) * Kd + kb + ksh[q], Bt + (q * 256 + wbase) * 8);
    __syncthreads();
#pragma unroll
    for (int kh = 0; kh < 2; ++kh) {
      int kbyte = ((kh << 6) | klo) ^ sw;
      fragT af[4], bf[NF];
#pragma unroll
      for (int m = 0; m < 4; ++m)
        af[m] = *(const fragT*)((const char*)At + (wr * 64 + m * 16 + lrow) * 128 + kbyte);
#pragma unroll
      for (int n = 0; n < NF; ++n)
        bf[n] = *(const fragT*)((const char*)Bt + (wc * NF * 16 + n * 16 + lrow) * 128 + kbyte);
#pragma unroll
      for (int m = 0; m < 4; ++m)
#pragma unroll
        for (int n = 0; n < NF; ++n)
          acc[m][n] = __builtin_amdgcn_mfma_f32_16x16x32_bf16(af[m], bf[n], acc[m][n], 0, 0, 0);
    }
    __syncthreads();
  }

  float local = 0.f;
#pragma unroll
  for (int m = 0; m < 4; ++m) {
    int row0 = m0 + wr * 64 + m * 16 + ((lane >> 4) << 2);
#pragma unroll
    for (int n = 0; n < NF; ++n) {
      int col = n0 + wc * NF * 16 + n * 16 + lrow;
      float bv = bias[col];
      f32x4 a = acc[m][n];
#pragma unroll
      for (int j = 0; j < 4; ++j) {
        float c = a[j] + bv;
        if (RELU) c = fmaxf(c, 0.f);
        if (FUSE) {
          float xv = Xref[(size_t)(row0 + j) * N + col];
          float d = c - xv;
          local = fmaf(d, d, local);
        }
        if (STBF) Cb[(size_t)(row0 + j) * N + col] = f2bf(c);
        if (STF32) Cf[(size_t)(row0 + j) * N + col] = c;
      }
    }
  }
  if (FUSE) {
#pragma unroll
    for (int off = 32; off >= 1; off >>= 1) local += __shfl_down(local, off);
    __shared__ float rs[4];
    if ((t & 63) == 0) rs[t >> 6] = local;
    __syncthreads();
    if (t == 0) atomicAdd(rec_sum, rs[0] + rs[1] + rs[2] + rs[3]);
  }
}

// ---------------- Gram over upper-triangular tile pairs + dual top-15 ----------------
// block = one 128x128 tile (rt<=ct); scans rows AND cols (cols skipped on diagonal).
// part[(slot*15+p)*8192 + i]: slot b in [0,64) = the opposing tile index.
__global__ __launch_bounds__(256) void k_gram_topk(
    const unsigned short* __restrict__ xb, const float* __restrict__ sqx,
    unsigned* __restrict__ part) {
  __shared__ __attribute__((aligned(16))) unsigned short At[128 * 64];  // 16KB
  __shared__ __attribute__((aligned(16))) unsigned short Bt[128 * 64];  // 16KB
  __shared__ float Sf[64 * 129];                                        // 33KB [col][row]
  __shared__ float sqr[128], sqc[128];

  unsigned* scratch = (unsigned*)At;  // reused after k-loop

  int bid0 = blockIdx.x;
  int bid = (bid0 & 7) * (NTILES / 8) + (bid0 >> 3);  // XCD-bijective swizzle
  // decode upper-tri (rt, ct), rt <= ct ; f(r) = 64r - r(r-1)/2
  float fr = 64.5f - sqrtf(64.5f * 64.5f - 2.0f * (float)bid);
  int rt = (int)fr;
  while (64 * (rt + 1) - ((rt + 1) * rt) / 2 <= bid) ++rt;
  while (64 * rt - (rt * (rt - 1)) / 2 > bid) --rt;
  int ct = rt + (bid - (64 * rt - (rt * (rt - 1)) / 2));
  bool diag = (rt == ct);
  int r0 = rt * 128, c0 = ct * 128;

  int t = threadIdx.x;
  int lane = t & 63, w = t >> 6;
  int wr = w >> 1, wc = w & 1;
  int wbase = w * 64;

  if (t < 128) {
    sqr[t] = sqx[r0 + t];
    sqc[t] = sqx[c0 + t];
  }

  int srow[4], ksh[4];
#pragma unroll
  for (int q = 0; q < 4; ++q) {
    int s = q * 256 + t;
    int r = s >> 3, g = s & 7;
    srow[q] = r;
    ksh[q] = (g ^ (r & 7)) * 8;
  }

  int lrow = lane & 15;
  int klo = (lane >> 4) << 4;
  int sw = (lane & 7) << 4;

  f32x4 acc[16] = {};

  for (int kt = 0; kt < 16; ++kt) {
    int kb = kt << 6;
#pragma unroll
    for (int q = 0; q < 4; ++q) {
      gload16(xb + (size_t)(r0 + srow[q]) * DD + kb + ksh[q], At + (q * 256 + wbase) * 8);
      gload16(xb + (size_t)(c0 + srow[q]) * DD + kb + ksh[q], Bt + (q * 256 + wbase) * 8);
    }
    __syncthreads();
#pragma unroll
    for (int kh = 0; kh < 2; ++kh) {
      int kbyte = ((kh << 6) | klo) ^ sw;
      fragT af[4], bf[4];
#pragma unroll
      for (int m = 0; m < 4; ++m)
        af[m] = *(const fragT*)((const char*)At + (wr * 64 + m * 16 + lrow) * 128 + kbyte);
#pragma unroll
      for (int n = 0; n < 4; ++n)
        bf[n] = *(const fragT*)((const char*)Bt + (wc * 64 + n * 16 + lrow) * 128 + kbyte);
#pragma unroll
      for (int m = 0; m < 4; ++m)
#pragma unroll
        for (int n = 0; n < 4; ++n)
          acc[m * 4 + n] =
              __builtin_amdgcn_mfma_f32_16x16x32_bf16(af[m], bf[n], acc[m * 4 + n], 0, 0, 0);
    }
    __syncthreads();
  }

  unsigned rowlist[KNN];
#pragma unroll
  for (int p = 0; p < KNN; ++p) rowlist[p] = 0xFFFFFFFFu;

  int scanrow = t & 127, side = t >> 7;

#pragma unroll
  for (int nh = 0; nh < 2; ++nh) {
    // write d2 half-tile (cols nh*64..+63) to Sf[colL][row], f32
    if (wc == nh) {
#pragma unroll
      for (int m = 0; m < 4; ++m) {
        int row0 = wr * 64 + m * 16 + ((lane >> 4) << 2);
        f32x4 sq4 = *(const f32x4*)&sqr[row0];
#pragma unroll
        for (int n = 0; n < 4; ++n) {
          int colL = n * 16 + lrow;
          float sc = sqc[nh * 64 + colL];
          f32x4 a = acc[m * 4 + n];
#pragma unroll
          for (int r = 0; r < 4; ++r) {
            float d2 = sq4[r] + sc - 2.f * a[r];
            if (diag && (row0 + r == nh * 64 + colL)) d2 = 60000.f;
            Sf[colL * 129 + row0 + r] = d2;
          }
        }
      }
    }
    __syncthreads();
    // row-scan: 2 threads/row, 32 cols each
    {
      int cbase = side * 32;
      for (int cc = 0; cc < 32; ++cc) {
        int colL = cbase + cc;
        float d = Sf[colL * 129 + scanrow];
        ins15(rowlist, packu(d, c0 + nh * 64 + colL));
      }
    }
    // col-scan (neighbors = rows of this tile), skip on diagonal
    if (!diag) {
      int c = t & 63, seg = t >> 6;
      unsigned collist[KNN];
#pragma unroll
      for (int p = 0; p < KNN; ++p) collist[p] = 0xFFFFFFFFu;
      for (int rr = 0; rr < 32; ++rr) {
        int r = seg * 32 + rr;
        float d = Sf[c * 129 + r];
        ins15(collist, packu(d, r0 + r));
      }
      __syncthreads();
#pragma unroll
      for (int p = 0; p < KNN; ++p) scratch[(c * 4 + seg) * KNN + p] = collist[p];
      __syncthreads();
      if (t < 64) {
        unsigned fin[KNN];
#pragma unroll
        for (int p = 0; p < KNN; ++p) fin[p] = 0xFFFFFFFFu;
        for (int s = 0; s < 4; ++s)
#pragma unroll
          for (int p = 0; p < KNN; ++p) ins15(fin, scratch[(t * 4 + s) * KNN + p]);
        int j = c0 + nh * 64 + t;
#pragma unroll
        for (int p = 0; p < KNN; ++p) part[((size_t)(rt * KNN + p)) * BB + j] = fin[p];
      }
    }
    __syncthreads();
  }

  // merge the 2 per-side row lists, write slot ct
#pragma unroll
  for (int p = 0; p < KNN; ++p) scratch[(scanrow * 2 + side) * KNN + p] = rowlist[p];
  __syncthreads();
  if (t < 128) {
    unsigned fin[KNN];
#pragma unroll
    for (int p = 0; p < KNN; ++p) fin[p] = 0xFFFFFFFFu;
    for (int s = 0; s < 2; ++s)
#pragma unroll
      for (int p = 0; p < KNN; ++p) ins15(fin, scratch[(t * 2 + s) * KNN + p]);
    int i = r0 + t;
#pragma unroll
    for (int p = 0; p < KNN; ++p) part[((size_t)(ct * KNN + p)) * BB + i] = fin[p];
  }
}

// ---------------- merge stage 1: 64 slots -> 4 ----------------
__global__ void k_merge1(const unsigned* __restrict__ part, unsigned* __restrict__ part2) {
  int gid = blockIdx.x * 256 + threadIdx.x;  // 32768
  int s = gid >> 13, i = gid & 8191;
  unsigned l[KNN];
#pragma unroll
  for (int p = 0; p < KNN; ++p) l[p] = 0xFFFFFFFFu;
  for (int b = s * 16; b < s * 16 + 16; ++b)
    for (int p = 0; p < KNN; ++p) ins15(l, part[((size_t)(b * KNN + p)) * BB + i]);
#pragma unroll
  for (int p = 0; p < KNN; ++p) part2[((size_t)(s * KNN + p)) * BB + i] = l[p];
}

// ---------------- merge stage 2: final top-15, Mdir, xmax ----------------
__global__ void k_merge2(const unsigned* __restrict__ part2, float* __restrict__ knn_d2,
                         int* __restrict__ knn_idx, unsigned* __restrict__ Mdir,
                         int* __restrict__ xmax_bits) {
  int i = blockIdx.x * 256 + threadIdx.x;
  unsigned l[KNN];
#pragma unroll
  for (int p = 0; p < KNN; ++p) l[p] = 0xFFFFFFFFu;
  for (int q = 0; q < 4 * KNN; ++q) ins15(l, part2[(size_t)q * BB + i]);
  float mx = 0.f;
#pragma unroll
  for (int p = 0; p < KNN; ++p) {
    unsigned u = l[p];
    float d = fmaxf(unpack_d2(u), 0.f);
    int j = (int)(u & 0xFFFFu);
    mx = fmaxf(mx, d);
    knn_d2[(size_t)i * KNN + p] = d;
    knn_idx[(size_t)i * KNN + p] = j;
    atomicOr(&Mdir[(size_t)i * (BB / 32) + (j >> 5)], 1u << (j & 31));
  }
  int t = threadIdx.x;
#pragma unroll
  for (int off = 32; off >= 1; off >>= 1) mx = fmaxf(mx, __shfl_down(mx, off));
  __shared__ float rm[4];
  if ((t & 63) == 0) rm[t >> 6] = mx;
  __syncthreads();
  if (t == 0) {
    float m = fmaxf(fmaxf(rm[0], rm[1]), fmaxf(rm[2], rm[3]));
    atomicMax(xmax_bits, __float_as_int(m));
  }
}

// ---------------- per-edge z distances ----------------
__global__ void k_edge_z(const float* __restrict__ z, const int* __restrict__ knn_idx,
                         float* __restrict__ zd2) {
  int e = blockIdx.x * 4 + (threadIdx.x >> 6);
  int lane = threadIdx.x & 63;
  int i = e / KNN;
  int j = knn_idx[e];
  float zi = z[(size_t)i * LL + lane];
  float zj = z[(size_t)j * LL + lane];
  float d = zi - zj;
  float v = d * d;
#pragma unroll
  for (int off = 32; off >= 1; off >>= 1) v += __shfl_down(v, off);
  if (lane == 0) zd2[e] = v;
}

__global__ void k_zmax(const float* __restrict__ zd2, int* __restrict__ zmax_bits) {
  int t = threadIdx.x;
  int idx = blockIdx.x * 256 + t;
  float mx = 0.f;
  for (int e = idx; e < NEDGE; e += 120 * 256) mx = fmaxf(mx, zd2[e]);
#pragma unroll
  for (int off = 32; off >= 1; off >>= 1) mx = fmaxf(mx, __shfl_down(mx, off));
  __shared__ float rm[4];
  if ((t & 63) == 0) rm[t >> 6] = mx;
  __syncthreads();
  if (t == 0) {
    float m = fmaxf(fmaxf(rm[0], rm[1]), fmaxf(rm[2], rm[3]));
    atomicMax(zmax_bits, __float_as_int(m));
  }
}

// ---------------- edge loss ----------------
__global__ void k_loss(const float* __restrict__ knn_d2, const int* __restrict__ knn_idx,
                       const float* __restrict__ zd2, const unsigned* __restrict__ Mdir,
                       const int* __restrict__ xmax_bits, const int* __restrict__ zmax_bits,
                       float* __restrict__ loss_sum, float* __restrict__ cnt_sum) {
  int e = blockIdx.x * 256 + threadIdx.x;
  float inv_x = 1.f / (sqrtf(__int_as_float(*xmax_bits)) + 1e-8f);
  float inv_z = 1.f / (sqrtf(__int_as_float(*zmax_bits)) + 1e-8f);
  int i = e / KNN;
  int j = knn_idx[e];
  unsigned bit = (Mdir[(size_t)j * (BB / 32) + (i >> 5)] >> (i & 31)) & 1u;
  float wgt = bit ? 1.f : 2.f;
  float xd = sqrtf(knn_d2[e]);
  float zd = sqrtf(fmaxf(zd2[e], 0.f));
  float diff = zd * inv_z - xd * inv_x;
  float c1 = wgt * diff * diff;
  float c2 = wgt;
#pragma unroll
  for (int off = 32; off >= 1; off >>= 1) {
    c1 += __shfl_down(c1, off);
    c2 += __shfl_down(c2, off);
  }
  __shared__ float r1[4], r2[4];
  int t = threadIdx.x;
  if ((t & 63) == 0) { r1[t >> 6] = c1; r2[t >> 6] = c2; }
  __syncthreads();
  if (t == 0) {
    atomicAdd(loss_sum, r1[0] + r1[1] + r1[2] + r1[3]);
    atomicAdd(cnt_sum, r2[0] + r2[1] + r2[2] + r2[3]);
  }
}

__global__ void k_final(const float* __restrict__ rec_sum, const float* __restrict__ loss_sum,
                        const float* __restrict__ cnt_sum, float* __restrict__ out) {
  if (threadIdx.x == 0)
    out[0] = rec_sum[0] * (1.f / 8388608.f) + loss_sum[0] / cnt_sum[0];
}

extern "C" void kernel_launch(void* const* d_in, const int* in_sizes, int n_in,
                              void* d_out, int out_size, void* d_ws, size_t ws_size,
                              hipStream_t stream) {
  const float* x = (const float*)d_in[0];
  const float* We1 = (const float*)d_in[1];
  const float* be1 = (const float*)d_in[2];
  const float* We2 = (const float*)d_in[3];
  const float* be2 = (const float*)d_in[4];
  const float* Wd1 = (const float*)d_in[5];
  const float* bd1 = (const float*)d_in[6];
  const float* Wd2 = (const float*)d_in[7];
  const float* bd2 = (const float*)d_in[8];

  char* ws = (char*)d_ws;
  size_t off = 0;
  auto alloc = [&](size_t bytes) {
    void* p = ws + off;
    off += (bytes + 255) & ~(size_t)255;
    return p;
  };
  unsigned short* xb = (unsigned short*)alloc((size_t)BB * DD * 2);
  unsigned short* hb = (unsigned short*)alloc((size_t)BB * HH * 2);
  unsigned short* zb = (unsigned short*)alloc((size_t)BB * LL * 2);
  unsigned short* h2b = (unsigned short*)alloc((size_t)BB * HH * 2);
  float* z = (float*)alloc((size_t)BB * LL * 4);
  float* sqx = (float*)alloc((size_t)BB * 4);
  unsigned short* Wt1 = (unsigned short*)alloc((size_t)HH * DD * 2);
  unsigned short* Wt2 = (unsigned short*)alloc((size_t)LL * HH * 2);
  unsigned short* Wt3 = (unsigned short*)alloc((size_t)HH * LL * 2);
  unsigned short* Wt4 = (unsigned short*)alloc((size_t)DD * HH * 2);
  unsigned* part = (unsigned*)alloc((size_t)NT * KNN * BB * 4);   // 31.5MB
  unsigned* part2 = (unsigned*)alloc((size_t)4 * KNN * BB * 4);   // 2MB
  float* knn_d2 = (float*)alloc((size_t)BB * KNN * 4);
  int* knn_idx = (int*)alloc((size_t)BB * KNN * 4);
  float* zd2 = (float*)alloc((size_t)BB * KNN * 4);
  unsigned* Mdir = (unsigned*)alloc((size_t)BB * (BB / 32) * 4);
  float* scal = (float*)alloc(64);
  float* rec_sum = scal + 0;
  float* loss_sum = scal + 1;
  float* cnt_sum = scal + 2;
  int* xmax_bits = (int*)(scal + 3);
  int* zmax_bits = (int*)(scal + 4);

  hipMemsetAsync(Mdir, 0, (size_t)BB * (BB / 32) * 4, stream);
  hipMemsetAsync(scal, 0, 64, stream);

  k_convert<<<BB, 256, 0, stream>>>(x, xb, sqx);
  k_wt<<<dim3(DD / 64, HH / 64), 256, 0, stream>>>(We1, Wt1, DD, HH);
  k_wt<<<dim3(HH / 64, LL / 64), 256, 0, stream>>>(We2, Wt2, HH, LL);
  k_wt<<<dim3(LL / 64, HH / 64), 256, 0, stream>>>(Wd1, Wt3, LL, HH);
  k_wt<<<dim3(HH / 64, DD / 64), 256, 0, stream>>>(Wd2, Wt4, HH, DD);

  k_gram_topk<<<NTILES, 256, 0, stream>>>(xb, sqx, part);

  k_mgemm<4, 1, 0, 0, 1><<<dim3(HH / 128, BB / 128), 256, 0, stream>>>(
      xb, Wt1, be1, hb, nullptr, nullptr, nullptr, HH, DD);
  k_mgemm<2, 0, 0, 1, 1><<<dim3(LL / 64, BB / 128), 256, 0, stream>>>(
      hb, Wt2, be2, zb, z, nullptr, nullptr, LL, HH);
  k_mgemm<4, 1, 0, 0, 1><<<dim3(HH / 128, BB / 128), 256, 0, stream>>>(
      zb, Wt3, bd1, h2b, nullptr, nullptr, nullptr, HH, LL);
  k_mgemm<4, 0, 1, 0, 0><<<dim3(DD / 128, BB / 128), 256, 0, stream>>>(
      h2b, Wt4, bd2, nullptr, nullptr, x, rec_sum, DD, HH);

  k_merge1<<<128, 256, 0, stream>>>(part, part2);
  k_merge2<<<BB / 256, 256, 0, stream>>>(part2, knn_d2, knn_idx, Mdir, xmax_bits);
  k_edge_z<<<NEDGE / 4, 256, 0, stream>>>(z, knn_idx, zd2);
  k_zmax<<<120, 256, 0, stream>>>(zd2, zmax_bits);
  k_loss<<<NEDGE / 256, 256, 0, stream>>>(knn_d2, knn_idx, zd2, Mdir, xmax_bits, zmax_bits,
                                          loss_sum, cnt_sum);
  k_final<<<1, 64, 0, stream>>>(rec_sum, loss_sum, cnt_sum, (float*)d_out);
}

// Round 6
// 434.391 us; speedup vs baseline: 8.4000x; 1.1368x over previous
//
#include <hip/hip_runtime.h>

#define BB 8192
#define DD 1024
#define HH 512
#define LL 64
#define KNN 15
#define NT 64            // 8192/128 tiles per dim
#define NTILES 2080      // NT*(NT+1)/2
#define NEDGE (BB * KNN)

typedef __attribute__((ext_vector_type(4))) float f32x4;
typedef __attribute__((ext_vector_type(8))) short s16x8;
typedef __attribute__((ext_vector_type(8))) unsigned short u16x8;
typedef __attribute__((ext_vector_type(4))) unsigned short u16x4;
typedef __attribute__((ext_vector_type(4))) _Float16 f16x4;

typedef s16x8 fragT;

__device__ __forceinline__ unsigned short f2bf(float f) {
  unsigned u = __float_as_uint(f);
  return (unsigned short)((u + 0x7fffu + ((u >> 16) & 1u)) >> 16);  // RNE
}

__device__ __forceinline__ void gload16(const void* g, void* l) {
  __builtin_amdgcn_global_load_lds((const __attribute__((address_space(1))) unsigned int*)g,
                                   (__attribute__((address_space(3))) unsigned int*)l, 16, 0, 0);
}

// packed candidate: f16(d2) in high 16 bits (monotonic for d2>=0), idx in low 16
__device__ __forceinline__ unsigned packu(float d2, int idx) {
  unsigned short hb = __builtin_bit_cast(unsigned short, (_Float16)d2);
  return ((unsigned)hb << 16) | (unsigned)idx;
}

__device__ __forceinline__ float unpack_d2(unsigned u) {
  _Float16 h = __builtin_bit_cast(_Float16, (unsigned short)(u >> 16));
  return (float)h;
}

// sorted ascending top-15 insert via min/max network
__device__ __forceinline__ void ins15(unsigned (&l)[KNN], unsigned u) {
  if (u < l[KNN - 1]) {
    unsigned v = u;
#pragma unroll
    for (int p = 0; p < KNN; ++p) {
      unsigned lo = min(v, l[p]);
      unsigned hi = max(v, l[p]);
      l[p] = lo;
      v = hi;
    }
  }
}

// ---------------- convert x -> bf16 + row norms ----------------
__global__ void k_convert(const float* __restrict__ x, unsigned short* __restrict__ xb,
                          float* __restrict__ sqx) {
  int row = blockIdx.x;
  int t = threadIdx.x;
  f32x4 v = *(const f32x4*)(x + (size_t)row * DD + t * 4);
  u16x4 o;
  float s = 0.f;
#pragma unroll
  for (int j = 0; j < 4; ++j) {
    float f = v[j];
    s += f * f;
    o[j] = f2bf(f);
  }
  *(u16x4*)(xb + (size_t)row * DD + t * 4) = o;
#pragma unroll
  for (int off = 32; off >= 1; off >>= 1) s += __shfl_down(s, off);
  __shared__ float ps[4];
  if ((t & 63) == 0) ps[t >> 6] = s;
  __syncthreads();
  if (t == 0) sqx[row] = ps[0] + ps[1] + ps[2] + ps[3];
}

// ---------------- weight transpose+convert ----------------
__global__ void k_wt(const float* __restrict__ W, unsigned short* __restrict__ Wt, int Kd, int N) {
  __shared__ unsigned short T[64][65];
  int k0 = blockIdx.x * 64, n0 = blockIdx.y * 64;
  int t = threadIdx.x;
  int kr = t >> 4, nc = (t & 15) * 4;
#pragma unroll
  for (int q = 0; q < 4; ++q) {
    int k = kr + q * 16;
    f32x4 v = *(const f32x4*)(W + (size_t)(k0 + k) * N + n0 + nc);
#pragma unroll
    for (int j = 0; j < 4; ++j) T[nc + j][k] = f2bf(v[j]);
  }
  __syncthreads();
#pragma unroll
  for (int q = 0; q < 2; ++q) {
    int s = t + q * 256;
    int n = s >> 3, c = (s & 7) * 8;
    u16x8 o;
#pragma unroll
    for (int j = 0; j < 8; ++j) o[j] = T[n][c + j];
    *(u16x8*)(Wt + (size_t)(n0 + n) * Kd + k0 + c) = o;
  }
}

// ---------------- bf16 MFMA GEMM ----------------
template <int NF, int RELU, int FUSE, int STF32, int STBF>
__global__ __launch_bounds__(256) void k_mgemm(
    const unsigned short* __restrict__ A, const unsigned short* __restrict__ Wt,
    const float* __restrict__ bias, unsigned short* __restrict__ Cb, float* __restrict__ Cf,
    const float* __restrict__ Xref, float* __restrict__ rec_sum, int N, int Kd) {
  __shared__ __attribute__((aligned(16))) unsigned short At[128 * 64];
  __shared__ __attribute__((aligned(16))) unsigned short Bt[NF * 32 * 64];
  int t = threadIdx.x;
  int lane = t & 63, w = t >> 6;
  int wr = w >> 1, wc = w & 1;
  int wbase = w * 64;
  int m0 = blockIdx.y * 128, n0 = blockIdx.x * (NF * 32);

  int srow[4], ksh[4];
#pragma unroll
  for (int q = 0; q < 4; ++q) {
    int s = q * 256 + t;
    int r = s >> 3, g = s & 7;
    srow[q] = r;
    ksh[q] = (g ^ (r & 7)) * 8;
  }

  int lrow = lane & 15;
  int klo = (lane >> 4) << 4;
  int sw = (lane & 7) << 4;

  f32x4 acc[4][NF] = {};

  int ksteps = Kd >> 6;
  for (int kt = 0; kt < ksteps; ++kt) {
    int kb = kt << 6;
#pragma unroll
    for (int q = 0; q < 4; ++q)
      gload16(A + (size_t)(m0 + srow[q]) * Kd + kb + ksh[q], At + (q * 256 + wbase) * 8);
#pragma unroll
    for (int q = 0; q < NF; ++q)
      gload16(Wt + (size_t)(n0 + srow[q]) * Kd + kb + ksh[q], Bt + (q * 256 + wbase) * 8);
    __syncthreads();
#pragma unroll
    for (int kh = 0; kh < 2; ++kh) {
      int kbyte = ((kh << 6) | klo) ^ sw;
      fragT af[4], bf[NF];
#pragma unroll
      for (int m = 0; m < 4; ++m)
        af[m] = *(const fragT*)((const char*)At + (wr * 64 + m * 16 + lrow) * 128 + kbyte);
#pragma unroll
      for (int n = 0; n < NF; ++n)
        bf[n] = *(const fragT*)((const char*)Bt + (wc * NF * 16 + n * 16 + lrow) * 128 + kbyte);
#pragma unroll
      for (int m = 0; m < 4; ++m)
#pragma unroll
        for (int n = 0; n < NF; ++n)
          acc[m][n] = __builtin_amdgcn_mfma_f32_16x16x32_bf16(af[m], bf[n], acc[m][n], 0, 0, 0);
    }
    __syncthreads();
  }

  float local = 0.f;
#pragma unroll
  for (int m = 0; m < 4; ++m) {
    int row0 = m0 + wr * 64 + m * 16 + ((lane >> 4) << 2);
#pragma unroll
    for (int n = 0; n < NF; ++n) {
      int col = n0 + wc * NF * 16 + n * 16 + lrow;
      float bv = bias[col];
      f32x4 a = acc[m][n];
#pragma unroll
      for (int j = 0; j < 4; ++j) {
        float c = a[j] + bv;
        if (RELU) c = fmaxf(c, 0.f);
        if (FUSE) {
          float xv = Xref[(size_t)(row0 + j) * N + col];
          float d = c - xv;
          local = fmaf(d, d, local);
        }
        if (STBF) Cb[(size_t)(row0 + j) * N + col] = f2bf(c);
        if (STF32) Cf[(size_t)(row0 + j) * N + col] = c;
      }
    }
  }
  if (FUSE) {
#pragma unroll
    for (int off = 32; off >= 1; off >>= 1) local += __shfl_down(local, off);
    __shared__ float rs[4];
    if ((t & 63) == 0) rs[t >> 6] = local;
    __syncthreads();
    if (t == 0) atomicAdd(rec_sum, rs[0] + rs[1] + rs[2] + rs[3]);
  }
}

// ---------------- Gram over upper-triangular tile pairs + dual top-15 ----------------
// LDS overlay: [0,16K) A-stage / Sf f16 half-tile; [16K,32K) B-stage / merge scratch.
// Sf layout: byte = colL*256 + ((row*2) ^ ((colL&31)<<3)); 33KB total -> 4 blocks/CU.
__global__ __launch_bounds__(256, 4) void k_gram_topk(
    const unsigned short* __restrict__ xb, const float* __restrict__ sqx,
    unsigned* __restrict__ part) {
  __shared__ __attribute__((aligned(16))) char LB[33792];
  unsigned short* At = (unsigned short*)LB;
  unsigned short* Bt = (unsigned short*)(LB + 16384);
  char* Sf = LB;                                  // scan phase (overlays At)
  unsigned* scratch = (unsigned*)(LB + 16384);    // scan phase (overlays Bt)
  float* sqr = (float*)(LB + 32768);
  float* sqc = (float*)(LB + 33280);

  int bid0 = blockIdx.x;
  int bid = (bid0 & 7) * (NTILES / 8) + (bid0 >> 3);  // XCD-bijective swizzle
  // decode upper-tri (rt, ct), rt <= ct
  float fr = 64.5f - sqrtf(64.5f * 64.5f - 2.0f * (float)bid);
  int rt = (int)fr;
  while (64 * (rt + 1) - ((rt + 1) * rt) / 2 <= bid) ++rt;
  while (64 * rt - (rt * (rt - 1)) / 2 > bid) --rt;
  int ct = rt + (bid - (64 * rt - (rt * (rt - 1)) / 2));
  bool diag = (rt == ct);
  int r0 = rt * 128, c0 = ct * 128;

  int t = threadIdx.x;
  int lane = t & 63, w = t >> 6;
  int wr = w >> 1, wc = w & 1;
  int wbase = w * 64;

  if (t < 128) {
    sqr[t] = sqx[r0 + t];
    sqc[t] = sqx[c0 + t];
  }

  int srow[4], ksh[4];
#pragma unroll
  for (int q = 0; q < 4; ++q) {
    int s = q * 256 + t;
    int r = s >> 3, g = s & 7;
    srow[q] = r;
    ksh[q] = (g ^ (r & 7)) * 8;
  }

  int lrow = lane & 15;
  int klo = (lane >> 4) << 4;
  int sw = (lane & 7) << 4;

  f32x4 acc[16] = {};

  for (int kt = 0; kt < 16; ++kt) {
    int kb = kt << 6;
#pragma unroll
    for (int q = 0; q < 4; ++q) {
      gload16(xb + (size_t)(r0 + srow[q]) * DD + kb + ksh[q], At + (q * 256 + wbase) * 8);
      gload16(xb + (size_t)(c0 + srow[q]) * DD + kb + ksh[q], Bt + (q * 256 + wbase) * 8);
    }
    __syncthreads();
#pragma unroll
    for (int kh = 0; kh < 2; ++kh) {
      int kbyte = ((kh << 6) | klo) ^ sw;
      fragT af[4], bf[4];
#pragma unroll
      for (int m = 0; m < 4; ++m)
        af[m] = *(const fragT*)((const char*)At + (wr * 64 + m * 16 + lrow) * 128 + kbyte);
#pragma unroll
      for (int n = 0; n < 4; ++n)
        bf[n] = *(const fragT*)((const char*)Bt + (wc * 64 + n * 16 + lrow) * 128 + kbyte);
#pragma unroll
      for (int m = 0; m < 4; ++m)
#pragma unroll
        for (int n = 0; n < 4; ++n)
          acc[m * 4 + n] =
              __builtin_amdgcn_mfma_f32_16x16x32_bf16(af[m], bf[n], acc[m * 4 + n], 0, 0, 0);
    }
    __syncthreads();
  }

  unsigned rowlist[KNN];
#pragma unroll
  for (int p = 0; p < KNN; ++p) rowlist[p] = 0xFFFFFFFFu;

  int scanrow = t & 127, side = t >> 7;

#pragma unroll
  for (int nh = 0; nh < 2; ++nh) {
    // write d2 half-tile (cols nh*64..+63) to swizzled f16 Sf (overlays A-stage)
    if (wc == nh) {
#pragma unroll
      for (int m = 0; m < 4; ++m) {
        int row0 = wr * 64 + m * 16 + ((lane >> 4) << 2);
        f32x4 sq4 = *(const f32x4*)&sqr[row0];
#pragma unroll
        for (int n = 0; n < 4; ++n) {
          int colL = n * 16 + lrow;
          float sc = sqc[nh * 64 + colL];
          f32x4 a = acc[m * 4 + n];
          f16x4 hv;
#pragma unroll
          for (int r = 0; r < 4; ++r) {
            float d2 = fmaxf(sq4[r] + sc - 2.f * a[r], 0.f);
            if (diag && (row0 + r == nh * 64 + colL)) d2 = 60000.f;
            hv[r] = (_Float16)d2;
          }
          *(f16x4*)(Sf + colL * 256 + (((row0 * 2)) ^ ((colL & 31) << 3))) = hv;
        }
      }
    }
    __syncthreads();
    // row-scan: 2 threads/row, 32 cols each
    {
      int cbase = side * 32;
      for (int cc = 0; cc < 32; ++cc) {
        int colL = cbase + cc;
        float d = (float)*(const _Float16*)(Sf + colL * 256 +
                                            ((scanrow * 2) ^ ((colL & 31) << 3)));
        ins15(rowlist, packu(d, c0 + nh * 64 + colL));
      }
    }
    // col-scan (neighbors = rows of this tile), skip on diagonal
    if (!diag) {
      int c = t & 63, seg = t >> 6;
      unsigned collist[KNN];
#pragma unroll
      for (int p = 0; p < KNN; ++p) collist[p] = 0xFFFFFFFFu;
      for (int rr = 0; rr < 32; ++rr) {
        int r = seg * 32 + rr;
        float d = (float)*(const _Float16*)(Sf + c * 256 + ((r * 2) ^ ((c & 31) << 3)));
        ins15(collist, packu(d, r0 + r));
      }
      __syncthreads();
#pragma unroll
      for (int p = 0; p < KNN; ++p) scratch[(c * 4 + seg) * KNN + p] = collist[p];
      __syncthreads();
      if (t < 64) {
        unsigned fin[KNN];
#pragma unroll
        for (int p = 0; p < KNN; ++p) fin[p] = 0xFFFFFFFFu;
        for (int s = 0; s < 4; ++s)
#pragma unroll
          for (int p = 0; p < KNN; ++p) ins15(fin, scratch[(t * 4 + s) * KNN + p]);
        int j = c0 + nh * 64 + t;
#pragma unroll
        for (int p = 0; p < KNN; ++p) part[((size_t)(rt * KNN + p)) * BB + j] = fin[p];
      }
    }
    __syncthreads();
  }

  // merge the 2 per-side row lists, write slot ct
#pragma unroll
  for (int p = 0; p < KNN; ++p) scratch[(scanrow * 2 + side) * KNN + p] = rowlist[p];
  __syncthreads();
  if (t < 128) {
    unsigned fin[KNN];
#pragma unroll
    for (int p = 0; p < KNN; ++p) fin[p] = 0xFFFFFFFFu;
    for (int s = 0; s < 2; ++s)
#pragma unroll
      for (int p = 0; p < KNN; ++p) ins15(fin, scratch[(t * 2 + s) * KNN + p]);
    int i = r0 + t;
#pragma unroll
    for (int p = 0; p < KNN; ++p) part[((size_t)(ct * KNN + p)) * BB + i] = fin[p];
  }
}

// ---------------- merge stage 1: 64 slots -> 4 ----------------
__global__ void k_merge1(const unsigned* __restrict__ part, unsigned* __restrict__ part2) {
  int gid = blockIdx.x * 256 + threadIdx.x;  // 32768
  int s = gid >> 13, i = gid & 8191;
  unsigned l[KNN];
#pragma unroll
  for (int p = 0; p < KNN; ++p) l[p] = 0xFFFFFFFFu;
  for (int b = s * 16; b < s * 16 + 16; ++b)
    for (int p = 0; p < KNN; ++p) ins15(l, part[((size_t)(b * KNN + p)) * BB + i]);
#pragma unroll
  for (int p = 0; p < KNN; ++p) part2[((size_t)(s * KNN + p)) * BB + i] = l[p];
}

// ---------------- merge stage 2: final top-15, Mdir, xmax ----------------
__global__ void k_merge2(const unsigned* __restrict__ part2, float* __restrict__ knn_d2,
                         int* __restrict__ knn_idx, unsigned* __restrict__ Mdir,
                         int* __restrict__ xmax_bits) {
  int i = blockIdx.x * 256 + threadIdx.x;
  unsigned l[KNN];
#pragma unroll
  for (int p = 0; p < KNN; ++p) l[p] = 0xFFFFFFFFu;
  for (int q = 0; q < 4 * KNN; ++q) ins15(l, part2[(size_t)q * BB + i]);
  float mx = 0.f;
#pragma unroll
  for (int p = 0; p < KNN; ++p) {
    unsigned u = l[p];
    float d = fmaxf(unpack_d2(u), 0.f);
    int j = (int)(u & 0xFFFFu);
    mx = fmaxf(mx, d);
    knn_d2[(size_t)i * KNN + p] = d;
    knn_idx[(size_t)i * KNN + p] = j;
    atomicOr(&Mdir[(size_t)i * (BB / 32) + (j >> 5)], 1u << (j & 31));
  }
  int t = threadIdx.x;
#pragma unroll
  for (int off = 32; off >= 1; off >>= 1) mx = fmaxf(mx, __shfl_down(mx, off));
  __shared__ float rm[4];
  if ((t & 63) == 0) rm[t >> 6] = mx;
  __syncthreads();
  if (t == 0) {
    float m = fmaxf(fmaxf(rm[0], rm[1]), fmaxf(rm[2], rm[3]));
    atomicMax(xmax_bits, __float_as_int(m));
  }
}

// ---------------- per-edge z distances ----------------
__global__ void k_edge_z(const float* __restrict__ z, const int* __restrict__ knn_idx,
                         float* __restrict__ zd2) {
  int e = blockIdx.x * 4 + (threadIdx.x >> 6);
  int lane = threadIdx.x & 63;
  int i = e / KNN;
  int j = knn_idx[e];
  float zi = z[(size_t)i * LL + lane];
  float zj = z[(size_t)j * LL + lane];
  float d = zi - zj;
  float v = d * d;
#pragma unroll
  for (int off = 32; off >= 1; off >>= 1) v += __shfl_down(v, off);
  if (lane == 0) zd2[e] = v;
}

__global__ void k_zmax(const float* __restrict__ zd2, int* __restrict__ zmax_bits) {
  int t = threadIdx.x;
  int idx = blockIdx.x * 256 + t;
  float mx = 0.f;
  for (int e = idx; e < NEDGE; e += 120 * 256) mx = fmaxf(mx, zd2[e]);
#pragma unroll
  for (int off = 32; off >= 1; off >>= 1) mx = fmaxf(mx, __shfl_down(mx, off));
  __shared__ float rm[4];
  if ((t & 63) == 0) rm[t >> 6] = mx;
  __syncthreads();
  if (t == 0) {
    float m = fmaxf(fmaxf(rm[0], rm[1]), fmaxf(rm[2], rm[3]));
    atomicMax(zmax_bits, __float_as_int(m));
  }
}

// ---------------- edge loss ----------------
__global__ void k_loss(const float* __restrict__ knn_d2, const int* __restrict__ knn_idx,
                       const float* __restrict__ zd2, const unsigned* __restrict__ Mdir,
                       const int* __restrict__ xmax_bits, const int* __restrict__ zmax_bits,
                       float* __restrict__ loss_sum, float* __restrict__ cnt_sum) {
  int e = blockIdx.x * 256 + threadIdx.x;
  float inv_x = 1.f / (sqrtf(__int_as_float(*xmax_bits)) + 1e-8f);
  float inv_z = 1.f / (sqrtf(__int_as_float(*zmax_bits)) + 1e-8f);
  int i = e / KNN;
  int j = knn_idx[e];
  unsigned bit = (Mdir[(size_t)j * (BB / 32) + (i >> 5)] >> (i & 31)) & 1u;
  float wgt = bit ? 1.f : 2.f;
  float xd = sqrtf(knn_d2[e]);
  float zd = sqrtf(fmaxf(zd2[e], 0.f));
  float diff = zd * inv_z - xd * inv_x;
  float c1 = wgt * diff * diff;
  float c2 = wgt;
#pragma unroll
  for (int off = 32; off >= 1; off >>= 1) {
    c1 += __shfl_down(c1, off);
    c2 += __shfl_down(c2, off);
  }
  __shared__ float r1[4], r2[4];
  int t = threadIdx.x;
  if ((t & 63) == 0) { r1[t >> 6] = c1; r2[t >> 6] = c2; }
  __syncthreads();
  if (t == 0) {
    atomicAdd(loss_sum, r1[0] + r1[1] + r1[2] + r1[3]);
    atomicAdd(cnt_sum, r2[0] + r2[1] + r2[2] + r2[3]);
  }
}

__global__ void k_final(const float* __restrict__ rec_sum, const float* __restrict__ loss_sum,
                        const float* __restrict__ cnt_sum, float* __restrict__ out) {
  if (threadIdx.x == 0)
    out[0] = rec_sum[0] * (1.f / 8388608.f) + loss_sum[0] / cnt_sum[0];
}

extern "C" void kernel_launch(void* const* d_in, const int* in_sizes, int n_in,
                              void* d_out, int out_size, void* d_ws, size_t ws_size,
                              hipStream_t stream) {
  const float* x = (const float*)d_in[0];
  const float* We1 = (const float*)d_in[1];
  const float* be1 = (const float*)d_in[2];
  const float* We2 = (const float*)d_in[3];
  const float* be2 = (const float*)d_in[4];
  const float* Wd1 = (const float*)d_in[5];
  const float* bd1 = (const float*)d_in[6];
  const float* Wd2 = (const float*)d_in[7];
  const float* bd2 = (const float*)d_in[8];

  char* ws = (char*)d_ws;
  size_t off = 0;
  auto alloc = [&](size_t bytes) {
    void* p = ws + off;
    off += (bytes + 255) & ~(size_t)255;
    return p;
  };
  unsigned short* xb = (unsigned short*)alloc((size_t)BB * DD * 2);
  unsigned short* hb = (unsigned short*)alloc((size_t)BB * HH * 2);
  unsigned short* zb = (unsigned short*)alloc((size_t)BB * LL * 2);
  unsigned short* h2b = (unsigned short*)alloc((size_t)BB * HH * 2);
  float* z = (float*)alloc((size_t)BB * LL * 4);
  float* sqx = (float*)alloc((size_t)BB * 4);
  unsigned short* Wt1 = (unsigned short*)alloc((size_t)HH * DD * 2);
  unsigned short* Wt2 = (unsigned short*)alloc((size_t)LL * HH * 2);
  unsigned short* Wt3 = (unsigned short*)alloc((size_t)HH * LL * 2);
  unsigned short* Wt4 = (unsigned short*)alloc((size_t)DD * HH * 2);
  unsigned* part = (unsigned*)alloc((size_t)NT * KNN * BB * 4);   // 31.5MB
  unsigned* part2 = (unsigned*)alloc((size_t)4 * KNN * BB * 4);   // 2MB
  float* knn_d2 = (float*)alloc((size_t)BB * KNN * 4);
  int* knn_idx = (int*)alloc((size_t)BB * KNN * 4);
  float* zd2 = (float*)alloc((size_t)BB * KNN * 4);
  unsigned* Mdir = (unsigned*)alloc((size_t)BB * (BB / 32) * 4);
  float* scal = (float*)alloc(64);
  float* rec_sum = scal + 0;
  float* loss_sum = scal + 1;
  float* cnt_sum = scal + 2;
  int* xmax_bits = (int*)(scal + 3);
  int* zmax_bits = (int*)(scal + 4);

  hipMemsetAsync(Mdir, 0, (size_t)BB * (BB / 32) * 4, stream);
  hipMemsetAsync(scal, 0, 64, stream);

  k_convert<<<BB, 256, 0, stream>>>(x, xb, sqx);
  k_wt<<<dim3(DD / 64, HH / 64), 256, 0, stream>>>(We1, Wt1, DD, HH);
  k_wt<<<dim3(HH / 64, LL / 64), 256, 0, stream>>>(We2, Wt2, HH, LL);
  k_wt<<<dim3(LL / 64, HH / 64), 256, 0, stream>>>(Wd1, Wt3, LL, HH);
  k_wt<<<dim3(HH / 64, DD / 64), 256, 0, stream>>>(Wd2, Wt4, HH, DD);

  k_gram_topk<<<NTILES, 256, 0, stream>>>(xb, sqx, part);

  k_mgemm<4, 1, 0, 0, 1><<<dim3(HH / 128, BB / 128), 256, 0, stream>>>(
      xb, Wt1, be1, hb, nullptr, nullptr, nullptr, HH, DD);
  k_mgemm<2, 0, 0, 1, 1><<<dim3(LL / 64, BB / 128), 256, 0, stream>>>(
      hb, Wt2, be2, zb, z, nullptr, nullptr, LL, HH);
  k_mgemm<4, 1, 0, 0, 1><<<dim3(HH / 128, BB / 128), 256, 0, stream>>>(
      zb, Wt3, bd1, h2b, nullptr, nullptr, nullptr, HH, LL);
  k_mgemm<4, 0, 1, 0, 0><<<dim3(DD / 128, BB / 128), 256, 0, stream>>>(
      h2b, Wt4, bd2, nullptr, nullptr, x, rec_sum, DD, HH);

  k_merge1<<<128, 256, 0, stream>>>(part, part2);
  k_merge2<<<BB / 256, 256, 0, stream>>>(part2, knn_d2, knn_idx, Mdir, xmax_bits);
  k_edge_z<<<NEDGE / 4, 256, 0, stream>>>(z, knn_idx, zd2);
  k_zmax<<<120, 256, 0, stream>>>(zd2, zmax_bits);
  k_loss<<<NEDGE / 256, 256, 0, stream>>>(knn_d2, knn_idx, zd2, Mdir, xmax_bits, zmax_bits,
                                          loss_sum, cnt_sum);
  k_final<<<1, 64, 0, stream>>>(rec_sum, loss_sum, cnt_sum, (float*)d_out);
}